// Round 12
// baseline (4041.991 us; speedup 1.0000x reference)
//
#include <hip/hip_runtime.h>
#include <cmath>

#define S_LEN 32
#define E_DIM 128
#define H_DIM 256
#define V_DIM 512
#define NTILE 36            // BK=64: pass1 18 (a1 x w1w2w3), pass2 12, pass3 6
#define TILE_SHORTS 8192    // 16 frags x 64 lanes x 8 shorts = 16 KB
#define A_SHORTS 24576      // 12 ksub x 4 rowblk x 64 lanes x 8 = 48 KB

typedef __attribute__((ext_vector_type(8))) short bf16x8v;
typedef __attribute__((ext_vector_type(4))) float f32x4v;

__device__ __forceinline__ float sigf(float x) { return 1.0f / (1.0f + expf(-x)); }

__device__ __forceinline__ unsigned short f2bf(float x) {      // RNE
  unsigned int b = __float_as_uint(x);
  b += 0x7FFFu + ((b >> 16) & 1u);
  return (unsigned short)(b >> 16);
}
__device__ __forceinline__ float bf2f(unsigned short u) {
  return __uint_as_float(((unsigned int)u) << 16);
}

template<int L>
__device__ __forceinline__ unsigned short lvl_bf(float x) {
  unsigned short b1 = f2bf(x);
  if (L == 1) return b1;
  float r1 = x - bf2f(b1);
  unsigned short b2 = f2bf(r1);
  if (L == 2) return b2;
  return f2bf(r1 - bf2f(b2));
}

__device__ __forceinline__ void gll16(const unsigned short* g, unsigned short* l) {
  __builtin_amdgcn_global_load_lds(
      (const __attribute__((address_space(1))) unsigned int*)g,
      (__attribute__((address_space(3))) unsigned int*)l, 16, 0, 0);
}

// ---------------------------------------------------------------------------
// prep: W fragment stream (BK=64 tiles) — EXACT round-9/11 layout + init tail.
// ---------------------------------------------------------------------------
__global__ void prep_weights(const float* __restrict__ eWih, const float* __restrict__ eWhh,
                             const float* __restrict__ dWih, const float* __restrict__ dWhh,
                             unsigned short* __restrict__ We, unsigned short* __restrict__ Wd,
                             float* __restrict__ h0, float* __restrict__ c,
                             int* __restrict__ tok)
{
  const int b = blockIdx.x;
  if (b >= 576) {                         // ---- init tail: 64 blocks
    const int pb = b - 576;
    const int gt = pb * 256 + threadIdx.x;     // 0..16383
    float4 z = make_float4(0.f, 0.f, 0.f, 0.f);
    float4* p0 = (float4*)h0;
    float4* pc = (float4*)c;
    for (int i = gt; i < 131072; i += 16384) { p0[i] = z; pc[i] = z; }
    if (gt < 2048) tok[gt] = 0;
    return;
  }
  const int j    = b % NTILE;
  const int rest = b / NTILE;
  const int nb   = rest & 7;
  const int set  = rest >> 3;
  const float* Wih = set ? dWih : eWih;
  const float* Whh = set ? dWhh : eWhh;
  unsigned short* dst = (set ? Wd : We) + ((size_t)nb * NTILE + j) * TILE_SHORTS;
  const int jj = (j < 18) ? j : (j < 30 ? j - 18 : j - 30);

  for (int cpos = threadIdx.x; cpos < 1024; cpos += 256) {
    int fi = cpos >> 6, l = cpos & 63;
    int kh = fi >> 3, wc = (fi >> 2) & 1, g = fi & 3;
    int n   = g * H_DIM + nb * 32 + wc * 16 + (l & 15);
    int sk0 = jj * 64 + kh * 32 + (l >> 4) * 8;
    int lvl = sk0 / 384;
    int kk  = sk0 - lvl * 384;
    unsigned short o8[8];
    #pragma unroll
    for (int e = 0; e < 8; ++e) {
      int k = kk + e;
      float v = (k < E_DIM) ? Wih[(size_t)n * E_DIM + k]
                            : Whh[(size_t)n * H_DIM + (k - E_DIM)];
      unsigned short b1 = f2bf(v);
      float r1 = v - bf2f(b1);
      unsigned short b2 = f2bf(r1);
      unsigned short b3 = f2bf(r1 - bf2f(b2));
      o8[e] = (lvl == 0) ? b1 : (lvl == 1) ? b2 : b3;
    }
    uint4 pk;
    pk.x = (unsigned)o8[0] | ((unsigned)o8[1] << 16);
    pk.y = (unsigned)o8[2] | ((unsigned)o8[3] << 16);
    pk.z = (unsigned)o8[4] | ((unsigned)o8[5] << 16);
    pk.w = (unsigned)o8[6] | ((unsigned)o8[7] << 16);
    *(uint4*)&dst[(size_t)cpos * 8] = pk;
  }
}

// stage level-L bf16 of A=[emb[idx]|h_in] into fragment layout — EXACT round-9/11
template<int L>
__device__ __forceinline__ void stage_A(unsigned short* Ax,
                                        const float* __restrict__ esrc,
                                        const float* __restrict__ hsrc,
                                        int arow, int q4) {
  const int rowblk = arow >> 4;
  const int rlo    = arow & 15;
  #pragma unroll
  for (int j = 0; j < 8; ++j) {
    int k0 = q4 * 4 + 16 * j;                 // 0..124
    float4 v = *(const float4*)(esrc + k0);
    unsigned short s0 = lvl_bf<L>(v.x), s1 = lvl_bf<L>(v.y),
                   s2 = lvl_bf<L>(v.z), s3 = lvl_bf<L>(v.w);
    uint2 p; p.x = (unsigned)s0 | ((unsigned)s1 << 16);
             p.y = (unsigned)s2 | ((unsigned)s3 << 16);
    int lane_w = rlo + ((k0 & 31) >> 3) * 16;
    *(uint2*)&Ax[(((k0 >> 5) * 4 + rowblk) * 64 + lane_w) * 8 + (k0 & 7)] = p;
  }
  #pragma unroll
  for (int j = 0; j < 16; ++j) {
    int k0 = q4 * 4 + 16 * j;                 // 0..252
    int kA = E_DIM + k0;
    float4 v = *(const float4*)(hsrc + k0);
    unsigned short s0 = lvl_bf<L>(v.x), s1 = lvl_bf<L>(v.y),
                   s2 = lvl_bf<L>(v.z), s3 = lvl_bf<L>(v.w);
    uint2 p; p.x = (unsigned)s0 | ((unsigned)s1 << 16);
             p.y = (unsigned)s2 | ((unsigned)s3 << 16);
    int lane_w = rlo + ((kA & 31) >> 3) * 16;
    *(uint2*)&Ax[(((kA >> 5) * 4 + rowblk) * 64 + lane_w) * 8 + (kA & 7)] = p;
  }
}

// ---------------------------------------------------------------------------
// LSTM step — numerics IDENTICAL to rounds 7-11; pipeline identical to r11.
// NEW (T1): 1-D grid, nb = bid & 7 so all 32 blocks reading weight-stream nb
// land on XCD nb (round-robin dispatch) -> per-XCD W working set 576 KB,
// L2-resident across steps (was 4.6 MB/XCD thrash with the 2-D grid).
// ---------------------------------------------------------------------------
__launch_bounds__(256)
__global__ void lstm_mfma_kernel(const float* __restrict__ emb,
                                 const int* __restrict__ idx_src, int idx_stride, int idx_off,
                                 const unsigned short* __restrict__ Wf,
                                 const float* __restrict__ bih, const float* __restrict__ bhh,
                                 const float* __restrict__ h_in,
                                 float* __restrict__ h_out, float* __restrict__ c)
{
  __shared__ __align__(16) unsigned short smem[A_SHORTS + 4 * TILE_SHORTS]; // 112 KB
  unsigned short* Ax    = smem;
  unsigned short* Bbase = smem + A_SHORTS;

  const int tid  = threadIdx.x;
  const int lane = tid & 63;
  const int w    = tid >> 6;
  const int bid  = blockIdx.x;
  const int nb   = bid & 7;           // XCD-local weight stream
  const int m0   = (bid >> 3) * 64;

  const int arow = tid >> 2;
  const int q4   = tid & 3;
  const int token = idx_src[(size_t)(m0 + arow) * idx_stride + idx_off];
  const float* esrc = emb + (size_t)token * E_DIM;
  const float* hsrc = h_in + (size_t)(m0 + arow) * H_DIM;

  const unsigned short* wstream = Wf + (size_t)nb * (NTILE * TILE_SHORTS);

  auto stage_B = [&](int j) {
    const unsigned short* src = wstream + (size_t)j * TILE_SHORTS + w * 2048 + lane * 8;
    unsigned short* dstp = Bbase + (size_t)(j & 3) * TILE_SHORTS + w * 2048;
    #pragma unroll
    for (int i = 0; i < 4; ++i) gll16(src + i * 512, dstp + i * 512);
  };

  stage_A<1>(Ax, esrc, hsrc, arow, q4);
  stage_B(0);
  stage_B(1);

  const int wm = (tid >> 6) & 1;
  const int wc = tid >> 7;

  f32x4v acc[2][4];
  #pragma unroll
  for (int mf = 0; mf < 2; ++mf)
    #pragma unroll
    for (int g = 0; g < 4; ++g)
      acc[mf][g] = (f32x4v){0.f, 0.f, 0.f, 0.f};

  #pragma unroll 1
  for (int j = 0; j < NTILE; ++j) {
    if (j == 18) { __builtin_amdgcn_s_barrier(); stage_A<2>(Ax, esrc, hsrc, arow, q4); }
    if (j == 30) { __builtin_amdgcn_s_barrier(); stage_A<3>(Ax, esrc, hsrc, arow, q4); }

    if (j < NTILE - 2) stage_B(j + 2);   // keep 2 tiles in flight

    if (j < NTILE - 2)       asm volatile("s_waitcnt vmcnt(8) lgkmcnt(0)" ::: "memory");
    else if (j == NTILE - 2) asm volatile("s_waitcnt vmcnt(4) lgkmcnt(0)" ::: "memory");
    else                     asm volatile("s_waitcnt vmcnt(0) lgkmcnt(0)" ::: "memory");
    __builtin_amdgcn_s_barrier();        // raw barrier: no vmcnt drain

    const unsigned short* cur = Bbase + (size_t)(j & 3) * TILE_SHORTS;
    const int jj  = (j < 18) ? j : (j < 30 ? j - 18 : j - 30);
    const int ks0 = (jj % 6) * 2;
    #pragma unroll
    for (int kh = 0; kh < 2; ++kh) {
      bf16x8v af0 = *(const bf16x8v*)&Ax[((ks0 + kh) * 4 + wm * 2) * 512 + lane * 8];
      bf16x8v af1 = *(const bf16x8v*)&Ax[((ks0 + kh) * 4 + wm * 2 + 1) * 512 + lane * 8];
      #pragma unroll
      for (int g = 0; g < 4; ++g) {
        bf16x8v bfr = *(const bf16x8v*)&cur[(kh * 8 + wc * 4 + g) * 512 + lane * 8];
        acc[0][g] = __builtin_amdgcn_mfma_f32_16x16x32_bf16(af0, bfr, acc[0][g], 0, 0, 0);
        acc[1][g] = __builtin_amdgcn_mfma_f32_16x16x32_bf16(af1, bfr, acc[1][g], 0, 0, 0);
      }
    }
  }

  // ---- epilogue: bias + cell update — EXACT rounds 7-11 version
  const int lr = tid & 15;
  const int l4 = lane >> 4;
  const int col = nb * 32 + wc * 16 + lr;
  float bs[4];
  #pragma unroll
  for (int g = 0; g < 4; ++g) bs[g] = bih[g * H_DIM + col] + bhh[g * H_DIM + col];

  #pragma unroll
  for (int mf = 0; mf < 2; ++mf) {
    #pragma unroll
    for (int r = 0; r < 4; ++r) {
      int row = m0 + wm * 32 + mf * 16 + l4 * 4 + r;
      float zi = acc[mf][0][r] + bs[0];
      float zf = acc[mf][1][r] + bs[1];
      float zg = acc[mf][2][r] + bs[2];
      float zo = acc[mf][3][r] + bs[3];
      float co = c[(size_t)row * H_DIM + col];
      float cn = sigf(zf) * co + sigf(zi) * tanhf(zg);
      c[(size_t)row * H_DIM + col] = cn;
      h_out[(size_t)row * H_DIM + col] = sigf(zo) * tanhf(cn);
    }
  }
}

// ---------------------------------------------------------------------------
// declog — EXACT round-9/11 version (known-good).
// ---------------------------------------------------------------------------
__launch_bounds__(256, 2)
__global__ void declog_kernel(const float* __restrict__ h,    // [B, H]
                              const float* __restrict__ fcW,  // [V, H]
                              const float* __restrict__ fcb,  // [V]
                              float* __restrict__ out,        // [B, T, V]
                              int* __restrict__ tok,          // [B]
                              int t, int T)
{
  __shared__ float As[8][264];
  __shared__ float Bs[2][16][V_DIM];

  const int tid  = threadIdx.x;
  const int lane = tid & 63;
  const int wv   = tid >> 6;
  const int r0   = blockIdx.x * 8;
  const int v0   = tid * 2;

  #pragma unroll
  for (int s = 0; s < 2; ++s) {
    int f4 = s * 256 + tid;
    int row = f4 >> 6, q = f4 & 63;
    float4 v = *(const float4*)(h + (size_t)(r0 + row) * H_DIM + q * 4);
    *(float4*)&As[row][q * 4] = v;
  }

  {
    #pragma unroll
    for (int s = 0; s < 2; ++s) {
      const float* src = fcW + (size_t)(v0 + s) * H_DIM;
      float4 w0 = *(const float4*)(src + 0);
      float4 w1 = *(const float4*)(src + 4);
      float4 w2 = *(const float4*)(src + 8);
      float4 w3 = *(const float4*)(src + 12);
      float wr[16] = {w0.x, w0.y, w0.z, w0.w, w1.x, w1.y, w1.z, w1.w,
                      w2.x, w2.y, w2.z, w2.w, w3.x, w3.y, w3.z, w3.w};
      #pragma unroll
      for (int q = 0; q < 16; ++q) Bs[0][q][v0 + s] = wr[q];
    }
  }
  __syncthreads();

  float acc[2][8] = {};

  #pragma unroll 1
  for (int j = 0; j < 16; ++j) {
    const int buf = j & 1;
    float wr[2][16];
    if (j < 15) {
      #pragma unroll
      for (int s = 0; s < 2; ++s) {
        const float* src = fcW + (size_t)(v0 + s) * H_DIM + (j + 1) * 16;
        float4 w0 = *(const float4*)(src + 0);
        float4 w1 = *(const float4*)(src + 4);
        float4 w2 = *(const float4*)(src + 8);
        float4 w3 = *(const float4*)(src + 12);
        wr[s][0]=w0.x; wr[s][1]=w0.y; wr[s][2]=w0.z; wr[s][3]=w0.w;
        wr[s][4]=w1.x; wr[s][5]=w1.y; wr[s][6]=w1.z; wr[s][7]=w1.w;
        wr[s][8]=w2.x; wr[s][9]=w2.y; wr[s][10]=w2.z; wr[s][11]=w2.w;
        wr[s][12]=w3.x; wr[s][13]=w3.y; wr[s][14]=w3.z; wr[s][15]=w3.w;
      }
    }
    const int k0 = j * 16;
    #pragma unroll
    for (int kk = 0; kk < 16; ++kk) {
      float a0 = As[wv * 2 + 0][k0 + kk];
      float a1 = As[wv * 2 + 1][k0 + kk];
      #pragma unroll
      for (int i = 0; i < 8; ++i) {
        float b = Bs[buf][kk][lane + 64 * i];
        acc[0][i] = fmaf(a0, b, acc[0][i]);
        acc[1][i] = fmaf(a1, b, acc[1][i]);
      }
    }
    if (j < 15) {
      #pragma unroll
      for (int s = 0; s < 2; ++s)
        #pragma unroll
        for (int q = 0; q < 16; ++q) Bs[buf ^ 1][q][v0 + s] = wr[s][q];
    }
    __syncthreads();
  }

  float bias[8];
  #pragma unroll
  for (int i = 0; i < 8; ++i) bias[i] = fcb[lane + 64 * i];

  #pragma unroll
  for (int r = 0; r < 2; ++r) {
    int row = r0 + wv * 2 + r;
    float* op = out + (size_t)row * T * V_DIM + (size_t)t * V_DIM;
    float best = -INFINITY;
    int   bi   = 0x7fffffff;
    #pragma unroll
    for (int i = 0; i < 8; ++i) {
      float x = acc[r][i] + bias[i];
      op[lane + 64 * i] = x;
      if (x > best) { best = x; bi = lane + 64 * i; }
    }
    #pragma unroll
    for (int off = 32; off; off >>= 1) {
      float ov = __shfl_xor(best, off);
      int   oi = __shfl_xor(bi, off);
      if (ov > best || (ov == best && oi < bi)) { best = ov; bi = oi; }
    }
    if (lane == 0) tok[row] = bi;
  }
}

extern "C" void kernel_launch(void* const* d_in, const int* in_sizes, int n_in,
                              void* d_out, int out_size, void* d_ws, size_t ws_size,
                              hipStream_t stream) {
  const int*   source  = (const int*)d_in[0];
  const float* enc_emb = (const float*)d_in[2];
  const float* enc_Wih = (const float*)d_in[3];
  const float* enc_Whh = (const float*)d_in[4];
  const float* enc_bih = (const float*)d_in[5];
  const float* enc_bhh = (const float*)d_in[6];
  const float* dec_emb = (const float*)d_in[7];
  const float* dec_Wih = (const float*)d_in[8];
  const float* dec_Whh = (const float*)d_in[9];
  const float* dec_bih = (const float*)d_in[10];
  const float* dec_bhh = (const float*)d_in[11];
  const float* fc_W    = (const float*)d_in[12];
  const float* fc_b    = (const float*)d_in[13];
  float* out = (float*)d_out;

  const int B = in_sizes[0] / S_LEN;              // 2048
  const int T = out_size / (B * V_DIM);           // 48

  const size_t BH = (size_t)B * H_DIM;
  const size_t WFSZ = (size_t)8 * NTILE * TILE_SHORTS;   // shorts per set
  float* h0  = (float*)d_ws;
  float* h1  = h0 + BH;
  float* c   = h1 + BH;
  int*   tok = (int*)(c + BH);
  unsigned short* We = (unsigned short*)(tok + B);
  unsigned short* Wd = We + WFSZ;

  prep_weights<<<dim3(576 + 64), dim3(256), 0, stream>>>(
      enc_Wih, enc_Whh, dec_Wih, dec_Whh, We, Wd, h0, c, tok);

  dim3 blk(256);
  dim3 g_lstm(256);                   // 1-D: nb = bid&7 (XCD-local), mb = bid>>3
  dim3 g_declog(B / 8);               // 256 blocks

  const float* hin = h0;
  float* hout = h1;

  // ---- encoder ----
  for (int s = 0; s < S_LEN; ++s) {
    lstm_mfma_kernel<<<g_lstm, blk, 0, stream>>>(
        enc_emb, source, S_LEN, s, We, enc_bih, enc_bhh, hin, hout, c);
    const float* tmp = hout; hout = (float*)hin; hin = tmp;
  }

  // ---- decoder (greedy, autoregressive) ----
  for (int t = 0; t < T; ++t) {
    lstm_mfma_kernel<<<g_lstm, blk, 0, stream>>>(
        dec_emb, tok, 1, 0, Wd, dec_bih, dec_bhh, hin, hout, c);
    const float* tmp = hout; hout = (float*)hin; hin = tmp;
    declog_kernel<<<g_declog, blk, 0, stream>>>(hin, fc_W, fc_b, out, tok, t, T);
  }
}

// Round 13
// 3138.467 us; speedup vs baseline: 1.2879x; 1.2879x over previous
//
#include <hip/hip_runtime.h>
#include <cmath>

#define S_LEN 32
#define E_DIM 128
#define H_DIM 256
#define V_DIM 512
#define NTILE 36            // BK=64: pass1 18 (a1 x w1w2w3), pass2 12, pass3 6
#define TILE_SHORTS 8192    // 16 frags x 64 lanes x 8 shorts = 16 KB
#define A_SHORTS 24576      // 12 ksub x 4 rowblk x 64 lanes x 8 = 48 KB

typedef __attribute__((ext_vector_type(8))) short bf16x8v;
typedef __attribute__((ext_vector_type(4))) float f32x4v;

__device__ __forceinline__ float sigf(float x) { return 1.0f / (1.0f + expf(-x)); }

__device__ __forceinline__ unsigned short f2bf(float x) {      // RNE
  unsigned int b = __float_as_uint(x);
  b += 0x7FFFu + ((b >> 16) & 1u);
  return (unsigned short)(b >> 16);
}
__device__ __forceinline__ float bf2f(unsigned short u) {
  return __uint_as_float(((unsigned int)u) << 16);
}

template<int L>
__device__ __forceinline__ unsigned short lvl_bf(float x) {
  unsigned short b1 = f2bf(x);
  if (L == 1) return b1;
  float r1 = x - bf2f(b1);
  unsigned short b2 = f2bf(r1);
  if (L == 2) return b2;
  return f2bf(r1 - bf2f(b2));
}

__device__ __forceinline__ void gll16(const unsigned short* g, unsigned short* l) {
  __builtin_amdgcn_global_load_lds(
      (const __attribute__((address_space(1))) unsigned int*)g,
      (__attribute__((address_space(3))) unsigned int*)l, 16, 0, 0);
}

// ---------------------------------------------------------------------------
// prep: W fragment stream (BK=64 tiles) — EXACT round-9/11 layout + init tail.
// ---------------------------------------------------------------------------
__global__ void prep_weights(const float* __restrict__ eWih, const float* __restrict__ eWhh,
                             const float* __restrict__ dWih, const float* __restrict__ dWhh,
                             unsigned short* __restrict__ We, unsigned short* __restrict__ Wd,
                             float* __restrict__ h0, float* __restrict__ c,
                             int* __restrict__ tok)
{
  const int b = blockIdx.x;
  if (b >= 576) {                         // ---- init tail: 64 blocks
    const int pb = b - 576;
    const int gt = pb * 256 + threadIdx.x;     // 0..16383
    float4 z = make_float4(0.f, 0.f, 0.f, 0.f);
    float4* p0 = (float4*)h0;
    float4* pc = (float4*)c;
    for (int i = gt; i < 131072; i += 16384) { p0[i] = z; pc[i] = z; }
    if (gt < 2048) tok[gt] = 0;
    return;
  }
  const int j    = b % NTILE;
  const int rest = b / NTILE;
  const int nb   = rest & 7;
  const int set  = rest >> 3;
  const float* Wih = set ? dWih : eWih;
  const float* Whh = set ? dWhh : eWhh;
  unsigned short* dst = (set ? Wd : We) + ((size_t)nb * NTILE + j) * TILE_SHORTS;
  const int jj = (j < 18) ? j : (j < 30 ? j - 18 : j - 30);

  for (int cpos = threadIdx.x; cpos < 1024; cpos += 256) {
    int fi = cpos >> 6, l = cpos & 63;
    int kh = fi >> 3, wc = (fi >> 2) & 1, g = fi & 3;
    int n   = g * H_DIM + nb * 32 + wc * 16 + (l & 15);
    int sk0 = jj * 64 + kh * 32 + (l >> 4) * 8;
    int lvl = sk0 / 384;
    int kk  = sk0 - lvl * 384;
    unsigned short o8[8];
    #pragma unroll
    for (int e = 0; e < 8; ++e) {
      int k = kk + e;
      float v = (k < E_DIM) ? Wih[(size_t)n * E_DIM + k]
                            : Whh[(size_t)n * H_DIM + (k - E_DIM)];
      unsigned short b1 = f2bf(v);
      float r1 = v - bf2f(b1);
      unsigned short b2 = f2bf(r1);
      unsigned short b3 = f2bf(r1 - bf2f(b2));
      o8[e] = (lvl == 0) ? b1 : (lvl == 1) ? b2 : b3;
    }
    uint4 pk;
    pk.x = (unsigned)o8[0] | ((unsigned)o8[1] << 16);
    pk.y = (unsigned)o8[2] | ((unsigned)o8[3] << 16);
    pk.z = (unsigned)o8[4] | ((unsigned)o8[5] << 16);
    pk.w = (unsigned)o8[6] | ((unsigned)o8[7] << 16);
    *(uint4*)&dst[(size_t)cpos * 8] = pk;
  }
}

// stage level-L bf16 of A=[emb[idx]|h_in] into fragment layout — EXACT round-9/11
template<int L>
__device__ __forceinline__ void stage_A(unsigned short* Ax,
                                        const float* __restrict__ esrc,
                                        const float* __restrict__ hsrc,
                                        int arow, int q4) {
  const int rowblk = arow >> 4;
  const int rlo    = arow & 15;
  #pragma unroll
  for (int j = 0; j < 8; ++j) {
    int k0 = q4 * 4 + 16 * j;                 // 0..124
    float4 v = *(const float4*)(esrc + k0);
    unsigned short s0 = lvl_bf<L>(v.x), s1 = lvl_bf<L>(v.y),
                   s2 = lvl_bf<L>(v.z), s3 = lvl_bf<L>(v.w);
    uint2 p; p.x = (unsigned)s0 | ((unsigned)s1 << 16);
             p.y = (unsigned)s2 | ((unsigned)s3 << 16);
    int lane_w = rlo + ((k0 & 31) >> 3) * 16;
    *(uint2*)&Ax[(((k0 >> 5) * 4 + rowblk) * 64 + lane_w) * 8 + (k0 & 7)] = p;
  }
  #pragma unroll
  for (int j = 0; j < 16; ++j) {
    int k0 = q4 * 4 + 16 * j;                 // 0..252
    int kA = E_DIM + k0;
    float4 v = *(const float4*)(hsrc + k0);
    unsigned short s0 = lvl_bf<L>(v.x), s1 = lvl_bf<L>(v.y),
                   s2 = lvl_bf<L>(v.z), s3 = lvl_bf<L>(v.w);
    uint2 p; p.x = (unsigned)s0 | ((unsigned)s1 << 16);
             p.y = (unsigned)s2 | ((unsigned)s3 << 16);
    int lane_w = rlo + ((kA & 31) >> 3) * 16;
    *(uint2*)&Ax[(((kA >> 5) * 4 + rowblk) * 64 + lane_w) * 8 + (kA & 7)] = p;
  }
}

// ---------------------------------------------------------------------------
// LSTM step — EXACT round-11 version (numerics identical to rounds 7-12;
// 4-deep B ring + counted vmcnt + raw s_barrier; grid (32,8)).
// ---------------------------------------------------------------------------
__launch_bounds__(256)
__global__ void lstm_mfma_kernel(const float* __restrict__ emb,
                                 const int* __restrict__ idx_src, int idx_stride, int idx_off,
                                 const unsigned short* __restrict__ Wf,
                                 const float* __restrict__ bih, const float* __restrict__ bhh,
                                 const float* __restrict__ h_in,
                                 float* __restrict__ h_out, float* __restrict__ c)
{
  __shared__ __align__(16) unsigned short smem[A_SHORTS + 4 * TILE_SHORTS]; // 112 KB
  unsigned short* Ax    = smem;
  unsigned short* Bbase = smem + A_SHORTS;

  const int tid  = threadIdx.x;
  const int lane = tid & 63;
  const int w    = tid >> 6;
  const int m0 = blockIdx.x * 64;
  const int nb = blockIdx.y;

  const int arow = tid >> 2;
  const int q4   = tid & 3;
  const int token = idx_src[(size_t)(m0 + arow) * idx_stride + idx_off];
  const float* esrc = emb + (size_t)token * E_DIM;
  const float* hsrc = h_in + (size_t)(m0 + arow) * H_DIM;

  const unsigned short* wstream = Wf + (size_t)nb * (NTILE * TILE_SHORTS);

  auto stage_B = [&](int j) {
    const unsigned short* src = wstream + (size_t)j * TILE_SHORTS + w * 2048 + lane * 8;
    unsigned short* dstp = Bbase + (size_t)(j & 3) * TILE_SHORTS + w * 2048;
    #pragma unroll
    for (int i = 0; i < 4; ++i) gll16(src + i * 512, dstp + i * 512);
  };

  stage_A<1>(Ax, esrc, hsrc, arow, q4);
  stage_B(0);
  stage_B(1);

  const int wm = (tid >> 6) & 1;
  const int wc = tid >> 7;

  f32x4v acc[2][4];
  #pragma unroll
  for (int mf = 0; mf < 2; ++mf)
    #pragma unroll
    for (int g = 0; g < 4; ++g)
      acc[mf][g] = (f32x4v){0.f, 0.f, 0.f, 0.f};

  #pragma unroll 1
  for (int j = 0; j < NTILE; ++j) {
    if (j == 18) { __builtin_amdgcn_s_barrier(); stage_A<2>(Ax, esrc, hsrc, arow, q4); }
    if (j == 30) { __builtin_amdgcn_s_barrier(); stage_A<3>(Ax, esrc, hsrc, arow, q4); }

    if (j < NTILE - 2) stage_B(j + 2);   // keep 2 tiles in flight

    if (j < NTILE - 2)       asm volatile("s_waitcnt vmcnt(8) lgkmcnt(0)" ::: "memory");
    else if (j == NTILE - 2) asm volatile("s_waitcnt vmcnt(4) lgkmcnt(0)" ::: "memory");
    else                     asm volatile("s_waitcnt vmcnt(0) lgkmcnt(0)" ::: "memory");
    __builtin_amdgcn_s_barrier();        // raw barrier: no vmcnt drain

    const unsigned short* cur = Bbase + (size_t)(j & 3) * TILE_SHORTS;
    const int jj  = (j < 18) ? j : (j < 30 ? j - 18 : j - 30);
    const int ks0 = (jj % 6) * 2;
    #pragma unroll
    for (int kh = 0; kh < 2; ++kh) {
      bf16x8v af0 = *(const bf16x8v*)&Ax[((ks0 + kh) * 4 + wm * 2) * 512 + lane * 8];
      bf16x8v af1 = *(const bf16x8v*)&Ax[((ks0 + kh) * 4 + wm * 2 + 1) * 512 + lane * 8];
      #pragma unroll
      for (int g = 0; g < 4; ++g) {
        bf16x8v bfr = *(const bf16x8v*)&cur[(kh * 8 + wc * 4 + g) * 512 + lane * 8];
        acc[0][g] = __builtin_amdgcn_mfma_f32_16x16x32_bf16(af0, bfr, acc[0][g], 0, 0, 0);
        acc[1][g] = __builtin_amdgcn_mfma_f32_16x16x32_bf16(af1, bfr, acc[1][g], 0, 0, 0);
      }
    }
  }

  // ---- epilogue: bias + cell update — EXACT rounds 7-12 version
  const int lr = tid & 15;
  const int l4 = lane >> 4;
  const int col = nb * 32 + wc * 16 + lr;
  float bs[4];
  #pragma unroll
  for (int g = 0; g < 4; ++g) bs[g] = bih[g * H_DIM + col] + bhh[g * H_DIM + col];

  #pragma unroll
  for (int mf = 0; mf < 2; ++mf) {
    #pragma unroll
    for (int r = 0; r < 4; ++r) {
      int row = m0 + wm * 32 + mf * 16 + l4 * 4 + r;
      float zi = acc[mf][0][r] + bs[0];
      float zf = acc[mf][1][r] + bs[1];
      float zg = acc[mf][2][r] + bs[2];
      float zo = acc[mf][3][r] + bs[3];
      float co = c[(size_t)row * H_DIM + col];
      float cn = sigf(zf) * co + sigf(zi) * tanhf(zg);
      c[(size_t)row * H_DIM + col] = cn;
      h_out[(size_t)row * H_DIM + col] = sigf(zo) * tanhf(cn);
    }
  }
}

// ---------------------------------------------------------------------------
// declog v4: no LDS GEMM staging at all.
//  - B: each thread streams its own 2 fcW rows from L2, 64-B-aligned float4
//    runs (full cache lines, fcW L2-resident).
//  - A: direct global reads at wave-uniform addresses (scalar/broadcast path).
//  - LDS only for the block argmax (round-4 proven reduction).
// FMA chain per output: k ascending 0..255 — BIT-IDENTICAL to rounds 2-12.
// ---------------------------------------------------------------------------
__launch_bounds__(256)
__global__ void declog_kernel(const float* __restrict__ h,    // [B, H]
                              const float* __restrict__ fcW,  // [V, H]
                              const float* __restrict__ fcb,  // [V]
                              float* __restrict__ out,        // [B, T, V]
                              int* __restrict__ tok,          // [B]
                              int t, int T)
{
  __shared__ float bv[8][256];
  __shared__ int   bi[8][256];

  const int tid  = threadIdx.x;
  const int lane = tid & 63;
  const int wv   = tid >> 6;
  const int r0   = blockIdx.x * 8;
  const int c0   = tid * 2;             // this thread's 2 vocab cols

  const float* hb  = h + (size_t)r0 * H_DIM;
  const float* w0p = fcW + (size_t)c0 * H_DIM;
  const float* w1p = w0p + H_DIM;

  float acc[8][2] = {};                 // [row][col]

  #pragma unroll 1
  for (int k0 = 0; k0 < H_DIM; k0 += 16) {
    float4 b0[4], b1[4];
    #pragma unroll
    for (int q = 0; q < 4; ++q) {
      b0[q] = *(const float4*)(w0p + k0 + q * 4);
      b1[q] = *(const float4*)(w1p + k0 + q * 4);
    }
    #pragma unroll
    for (int q = 0; q < 4; ++q) {
      #pragma unroll
      for (int r = 0; r < 8; ++r) {
        float4 a = *(const float4*)(hb + (size_t)r * H_DIM + k0 + q * 4); // uniform
        acc[r][0] = fmaf(a.x, b0[q].x, acc[r][0]);
        acc[r][0] = fmaf(a.y, b0[q].y, acc[r][0]);
        acc[r][0] = fmaf(a.z, b0[q].z, acc[r][0]);
        acc[r][0] = fmaf(a.w, b0[q].w, acc[r][0]);
        acc[r][1] = fmaf(a.x, b1[q].x, acc[r][1]);
        acc[r][1] = fmaf(a.y, b1[q].y, acc[r][1]);
        acc[r][1] = fmaf(a.z, b1[q].z, acc[r][1]);
        acc[r][1] = fmaf(a.w, b1[q].w, acc[r][1]);
      }
    }
  }

  // ---- bias, store logits, per-thread argmax candidates
  const float fb0 = fcb[c0];
  const float fb1 = fcb[c0 + 1];
  #pragma unroll
  for (int r = 0; r < 8; ++r) {
    float z0 = acc[r][0] + fb0;
    float z1 = acc[r][1] + fb1;
    *(float2*)(out + (size_t)(r0 + r) * T * V_DIM + (size_t)t * V_DIM + c0)
        = make_float2(z0, z1);
    float v = z0; int ix = c0;
    if (z1 > v) { v = z1; ix = c0 + 1; }   // strict >: first index kept
    bv[r][tid] = v;
    bi[r][tid] = ix;
  }
  __syncthreads();

  // ---- block argmax: wave wv reduces rows 2wv, 2wv+1 (round-4 proven)
  #pragma unroll
  for (int rr = 0; rr < 2; ++rr) {
    int r = wv * 2 + rr;
    float best = bv[r][lane];
    int   bidx = bi[r][lane];
    #pragma unroll
    for (int s = 1; s < 4; ++s) {
      float ov = bv[r][lane + 64 * s];
      int   oi = bi[r][lane + 64 * s];
      if (ov > best || (ov == best && oi < bidx)) { best = ov; bidx = oi; }
    }
    #pragma unroll
    for (int off = 32; off; off >>= 1) {
      float ov = __shfl_xor(best, off);
      int   oi = __shfl_xor(bidx, off);
      if (ov > best || (ov == best && oi < bidx)) { best = ov; bidx = oi; }
    }
    if (lane == 0) tok[r0 + r] = bidx;
  }
}

extern "C" void kernel_launch(void* const* d_in, const int* in_sizes, int n_in,
                              void* d_out, int out_size, void* d_ws, size_t ws_size,
                              hipStream_t stream) {
  const int*   source  = (const int*)d_in[0];
  const float* enc_emb = (const float*)d_in[2];
  const float* enc_Wih = (const float*)d_in[3];
  const float* enc_Whh = (const float*)d_in[4];
  const float* enc_bih = (const float*)d_in[5];
  const float* enc_bhh = (const float*)d_in[6];
  const float* dec_emb = (const float*)d_in[7];
  const float* dec_Wih = (const float*)d_in[8];
  const float* dec_Whh = (const float*)d_in[9];
  const float* dec_bih = (const float*)d_in[10];
  const float* dec_bhh = (const float*)d_in[11];
  const float* fc_W    = (const float*)d_in[12];
  const float* fc_b    = (const float*)d_in[13];
  float* out = (float*)d_out;

  const int B = in_sizes[0] / S_LEN;              // 2048
  const int T = out_size / (B * V_DIM);           // 48

  const size_t BH = (size_t)B * H_DIM;
  const size_t WFSZ = (size_t)8 * NTILE * TILE_SHORTS;   // shorts per set
  float* h0  = (float*)d_ws;
  float* h1  = h0 + BH;
  float* c   = h1 + BH;
  int*   tok = (int*)(c + BH);
  unsigned short* We = (unsigned short*)(tok + B);
  unsigned short* Wd = We + WFSZ;

  prep_weights<<<dim3(576 + 64), dim3(256), 0, stream>>>(
      enc_Wih, enc_Whh, dec_Wih, dec_Whh, We, Wd, h0, c, tok);

  dim3 blk(256);
  dim3 g_lstm(B / 64, H_DIM / 32);    // (32, 8) = 256 blocks (round-11 mapping)
  dim3 g_declog(B / 8);               // 256 blocks

  const float* hin = h0;
  float* hout = h1;

  // ---- encoder ----
  for (int s = 0; s < S_LEN; ++s) {
    lstm_mfma_kernel<<<g_lstm, blk, 0, stream>>>(
        enc_emb, source, S_LEN, s, We, enc_bih, enc_bhh, hin, hout, c);
    const float* tmp = hout; hout = (float*)hin; hin = tmp;
  }

  // ---- decoder (greedy, autoregressive) ----
  for (int t = 0; t < T; ++t) {
    lstm_mfma_kernel<<<g_lstm, blk, 0, stream>>>(
        dec_emb, tok, 1, 0, Wd, dec_bih, dec_bhh, hin, hout, c);
    const float* tmp = hout; hout = (float*)hin; hin = tmp;
    declog_kernel<<<g_declog, blk, 0, stream>>>(hin, fc_W, fc_b, out, tok, t, T);
  }
}

// Round 14
// 2363.058 us; speedup vs baseline: 1.7105x; 1.3281x over previous
//
#include <hip/hip_runtime.h>
#include <cmath>

#define S_LEN 32
#define E_DIM 128
#define H_DIM 256
#define V_DIM 512
#define NTILE 18            // fp16 split: pass1 12 (a1 x [w1|w2s]), pass2 6 (a2s x w1)
#define W_TILES 12          // unique W tiles stored (tiles 12-17 reuse 0-5)
#define TILE_SHORTS 8192    // 16 frags x 64 lanes x 8 halfs = 16 KB
#define A_SHORTS 24576      // 12 ksub x 4 rowblk x 64 lanes x 8 = 48 KB

typedef __attribute__((ext_vector_type(8))) short bf16x8v;
typedef _Float16 f16x8v __attribute__((ext_vector_type(8)));
typedef __attribute__((ext_vector_type(4))) float f32x4v;

#define SCALE_S 4096.0f          // 2^12
#define INV_S   2.44140625e-4f   // 2^-12 (exact)

__device__ __forceinline__ float sigf(float x) { return 1.0f / (1.0f + expf(-x)); }

// level-L fp16 component: x ~= h1 + h2*2^-12 + O(2^-22 x); h2 stored pre-scaled
template<int L>
__device__ __forceinline__ unsigned short lvl_f16(float x) {
  _Float16 h1 = (_Float16)x;                       // RNE
  if (L == 1) return __builtin_bit_cast(unsigned short, h1);
  _Float16 h2 = (_Float16)((x - (float)h1) * SCALE_S);
  return __builtin_bit_cast(unsigned short, h2);
}

__device__ __forceinline__ void gll16(const unsigned short* g, unsigned short* l) {
  __builtin_amdgcn_global_load_lds(
      (const __attribute__((address_space(1))) unsigned int*)g,
      (__attribute__((address_space(3))) unsigned int*)l, 16, 0, 0);
}

// ---------------------------------------------------------------------------
// prep: W fragment stream, fp16 2-level. 12 tiles per (set, nb):
//   tiles 0..5  = w1  (k = j*64 .. +63)
//   tiles 6..11 = w2s (k = (j-6)*64 .. +63), w2s = f16((w - f32(w1)) * 2^12)
// Fragment layout within a tile: EXACT rounds 9-13 mapping.
// Blocks >= 192 zero-init h0 / c / tok.
// ---------------------------------------------------------------------------
__global__ void prep_weights(const float* __restrict__ eWih, const float* __restrict__ eWhh,
                             const float* __restrict__ dWih, const float* __restrict__ dWhh,
                             unsigned short* __restrict__ We, unsigned short* __restrict__ Wd,
                             float* __restrict__ h0, float* __restrict__ c,
                             int* __restrict__ tok)
{
  const int b = blockIdx.x;
  if (b >= 192) {                         // ---- init tail: 64 blocks
    const int pb = b - 192;
    const int gt = pb * 256 + threadIdx.x;     // 0..16383
    float4 z = make_float4(0.f, 0.f, 0.f, 0.f);
    float4* p0 = (float4*)h0;
    float4* pc = (float4*)c;
    for (int i = gt; i < 131072; i += 16384) { p0[i] = z; pc[i] = z; }
    if (gt < 2048) tok[gt] = 0;
    return;
  }
  const int j    = b % W_TILES;           // 0..11
  const int rest = b / W_TILES;
  const int nb   = rest & 7;
  const int set  = rest >> 3;
  const float* Wih = set ? dWih : eWih;
  const float* Whh = set ? dWhh : eWhh;
  unsigned short* dst = (set ? Wd : We) + ((size_t)nb * W_TILES + j) * TILE_SHORTS;
  const int lvl = (j < 6) ? 1 : 2;
  const int jj  = (j < 6) ? j : j - 6;

  for (int cpos = threadIdx.x; cpos < 1024; cpos += 256) {
    int fi = cpos >> 6, l = cpos & 63;
    int kh = fi >> 3, wc = (fi >> 2) & 1, g = fi & 3;
    int n  = g * H_DIM + nb * 32 + wc * 16 + (l & 15);
    int kk = jj * 64 + kh * 32 + (l >> 4) * 8;
    unsigned short o8[8];
    #pragma unroll
    for (int e = 0; e < 8; ++e) {
      int k = kk + e;
      float v = (k < E_DIM) ? Wih[(size_t)n * E_DIM + k]
                            : Whh[(size_t)n * H_DIM + (k - E_DIM)];
      o8[e] = (lvl == 1) ? lvl_f16<1>(v) : lvl_f16<2>(v);
    }
    uint4 pk;
    pk.x = (unsigned)o8[0] | ((unsigned)o8[1] << 16);
    pk.y = (unsigned)o8[2] | ((unsigned)o8[3] << 16);
    pk.z = (unsigned)o8[4] | ((unsigned)o8[5] << 16);
    pk.w = (unsigned)o8[6] | ((unsigned)o8[7] << 16);
    *(uint4*)&dst[(size_t)cpos * 8] = pk;
  }
}

// stage level-L fp16 of A=[emb[idx]|h_in] into fragment layout (rounds 9-13 map)
template<int L>
__device__ __forceinline__ void stage_A(unsigned short* Ax,
                                        const float* __restrict__ esrc,
                                        const float* __restrict__ hsrc,
                                        int arow, int q4) {
  const int rowblk = arow >> 4;
  const int rlo    = arow & 15;
  #pragma unroll
  for (int j = 0; j < 8; ++j) {
    int k0 = q4 * 4 + 16 * j;                 // 0..124
    float4 v = *(const float4*)(esrc + k0);
    unsigned short s0 = lvl_f16<L>(v.x), s1 = lvl_f16<L>(v.y),
                   s2 = lvl_f16<L>(v.z), s3 = lvl_f16<L>(v.w);
    uint2 p; p.x = (unsigned)s0 | ((unsigned)s1 << 16);
             p.y = (unsigned)s2 | ((unsigned)s3 << 16);
    int lane_w = rlo + ((k0 & 31) >> 3) * 16;
    *(uint2*)&Ax[(((k0 >> 5) * 4 + rowblk) * 64 + lane_w) * 8 + (k0 & 7)] = p;
  }
  #pragma unroll
  for (int j = 0; j < 16; ++j) {
    int k0 = q4 * 4 + 16 * j;                 // 0..252
    int kA = E_DIM + k0;
    float4 v = *(const float4*)(hsrc + k0);
    unsigned short s0 = lvl_f16<L>(v.x), s1 = lvl_f16<L>(v.y),
                   s2 = lvl_f16<L>(v.z), s3 = lvl_f16<L>(v.w);
    uint2 p; p.x = (unsigned)s0 | ((unsigned)s1 << 16);
             p.y = (unsigned)s2 | ((unsigned)s3 << 16);
    int lane_w = rlo + ((kA & 31) >> 3) * 16;
    *(uint2*)&Ax[(((kA >> 5) * 4 + rowblk) * 64 + lane_w) * 8 + (kA & 7)] = p;
  }
}

// ---------------------------------------------------------------------------
// LSTM step, fp16 2-level 3-term split MFMA (K_eff 1152, was 2304).
//   tiles 0..5  : a1 x w1   -> accA (scale 1)
//   tiles 6..11 : a1 x w2s  -> accB (scale 2^-12)
//   tiles 12..17: a2s x w1  -> accB (scale 2^-12; W reuses tiles 0..5 data)
// Pipeline: 4-deep B ring + counted vmcnt + raw s_barrier (r11 proven).
// Epilogue: z = fma(accB, 2^-12, accA) + bias -> cell update (r7 formulas).
// ---------------------------------------------------------------------------
__launch_bounds__(256)
__global__ void lstm_mfma_kernel(const float* __restrict__ emb,
                                 const int* __restrict__ idx_src, int idx_stride, int idx_off,
                                 const unsigned short* __restrict__ Wf,
                                 const float* __restrict__ bih, const float* __restrict__ bhh,
                                 const float* __restrict__ h_in,
                                 float* __restrict__ h_out, float* __restrict__ c)
{
  __shared__ __align__(16) unsigned short smem[A_SHORTS + 4 * TILE_SHORTS]; // 112 KB
  unsigned short* Ax    = smem;
  unsigned short* Bbase = smem + A_SHORTS;

  const int tid  = threadIdx.x;
  const int lane = tid & 63;
  const int w    = tid >> 6;
  const int m0 = blockIdx.x * 64;
  const int nb = blockIdx.y;

  const int arow = tid >> 2;
  const int q4   = tid & 3;
  const int token = idx_src[(size_t)(m0 + arow) * idx_stride + idx_off];
  const float* esrc = emb + (size_t)token * E_DIM;
  const float* hsrc = h_in + (size_t)(m0 + arow) * H_DIM;

  const unsigned short* wstream = Wf + (size_t)nb * (W_TILES * TILE_SHORTS);

  auto stage_B = [&](int j) {
    const int jeff = (j < W_TILES) ? j : j - W_TILES;   // tiles 12-17 reuse 0-5
    const unsigned short* src = wstream + (size_t)jeff * TILE_SHORTS + w * 2048 + lane * 8;
    unsigned short* dstp = Bbase + (size_t)(j & 3) * TILE_SHORTS + w * 2048;
    #pragma unroll
    for (int i = 0; i < 4; ++i) gll16(src + i * 512, dstp + i * 512);
  };

  stage_A<1>(Ax, esrc, hsrc, arow, q4);
  stage_B(0);
  stage_B(1);

  const int wm = (tid >> 6) & 1;
  const int wc = tid >> 7;

  f32x4v accA[2][4], accB[2][4];
  #pragma unroll
  for (int mf = 0; mf < 2; ++mf)
    #pragma unroll
    for (int g = 0; g < 4; ++g) {
      accA[mf][g] = (f32x4v){0.f, 0.f, 0.f, 0.f};
      accB[mf][g] = (f32x4v){0.f, 0.f, 0.f, 0.f};
    }

  auto mfma_tile = [&](f32x4v (&acc)[2][4], const unsigned short* cur, int ks0) {
    #pragma unroll
    for (int kh = 0; kh < 2; ++kh) {
      f16x8v af0 = *(const f16x8v*)&Ax[((ks0 + kh) * 4 + wm * 2) * 512 + lane * 8];
      f16x8v af1 = *(const f16x8v*)&Ax[((ks0 + kh) * 4 + wm * 2 + 1) * 512 + lane * 8];
      #pragma unroll
      for (int g = 0; g < 4; ++g) {
        f16x8v bfr = *(const f16x8v*)&cur[(kh * 8 + wc * 4 + g) * 512 + lane * 8];
        acc[0][g] = __builtin_amdgcn_mfma_f32_16x16x32_f16(af0, bfr, acc[0][g], 0, 0, 0);
        acc[1][g] = __builtin_amdgcn_mfma_f32_16x16x32_f16(af1, bfr, acc[1][g], 0, 0, 0);
      }
    }
  };

  #pragma unroll 1
  for (int j = 0; j < NTILE; ++j) {
    // A-level switch: barrier orders restage writes after tile-11 A reads
    if (j == 12) { __builtin_amdgcn_s_barrier(); stage_A<2>(Ax, esrc, hsrc, arow, q4); }

    if (j < NTILE - 2) stage_B(j + 2);   // keep 2 tiles in flight

    if (j < NTILE - 2)       asm volatile("s_waitcnt vmcnt(8) lgkmcnt(0)" ::: "memory");
    else if (j == NTILE - 2) asm volatile("s_waitcnt vmcnt(4) lgkmcnt(0)" ::: "memory");
    else                     asm volatile("s_waitcnt vmcnt(0) lgkmcnt(0)" ::: "memory");
    __builtin_amdgcn_s_barrier();        // raw barrier: no vmcnt drain

    const unsigned short* cur = Bbase + (size_t)(j & 3) * TILE_SHORTS;
    const int jj  = (j < 6) ? j : (j < 12 ? j - 6 : j - 12);
    const int ks0 = jj * 2;
    if (j < 6) mfma_tile(accA, cur, ks0);
    else       mfma_tile(accB, cur, ks0);
  }

  // ---- epilogue: combine scales, bias + cell update (r7 cell formulas)
  const int lr = tid & 15;
  const int l4 = lane >> 4;
  const int col = nb * 32 + wc * 16 + lr;
  float bs[4];
  #pragma unroll
  for (int g = 0; g < 4; ++g) bs[g] = bih[g * H_DIM + col] + bhh[g * H_DIM + col];

  #pragma unroll
  for (int mf = 0; mf < 2; ++mf) {
    #pragma unroll
    for (int r = 0; r < 4; ++r) {
      int row = m0 + wm * 32 + mf * 16 + l4 * 4 + r;
      float zi = fmaf(accB[mf][0][r], INV_S, accA[mf][0][r]) + bs[0];
      float zf = fmaf(accB[mf][1][r], INV_S, accA[mf][1][r]) + bs[1];
      float zg = fmaf(accB[mf][2][r], INV_S, accA[mf][2][r]) + bs[2];
      float zo = fmaf(accB[mf][3][r], INV_S, accA[mf][3][r]) + bs[3];
      float co = c[(size_t)row * H_DIM + col];
      float cn = sigf(zf) * co + sigf(zi) * tanhf(zg);
      c[(size_t)row * H_DIM + col] = cn;
      h_out[(size_t)row * H_DIM + col] = sigf(zo) * tanhf(cn);
    }
  }
}

// ---------------------------------------------------------------------------
// declog v4 — EXACT round-13 version (known-good, ~6 us).
// ---------------------------------------------------------------------------
__launch_bounds__(256)
__global__ void declog_kernel(const float* __restrict__ h,    // [B, H]
                              const float* __restrict__ fcW,  // [V, H]
                              const float* __restrict__ fcb,  // [V]
                              float* __restrict__ out,        // [B, T, V]
                              int* __restrict__ tok,          // [B]
                              int t, int T)
{
  __shared__ float bv[8][256];
  __shared__ int   bi[8][256];

  const int tid  = threadIdx.x;
  const int lane = tid & 63;
  const int wv   = tid >> 6;
  const int r0   = blockIdx.x * 8;
  const int c0   = tid * 2;             // this thread's 2 vocab cols

  const float* hb  = h + (size_t)r0 * H_DIM;
  const float* w0p = fcW + (size_t)c0 * H_DIM;
  const float* w1p = w0p + H_DIM;

  float acc[8][2] = {};                 // [row][col]

  #pragma unroll 1
  for (int k0 = 0; k0 < H_DIM; k0 += 16) {
    float4 b0[4], b1[4];
    #pragma unroll
    for (int q = 0; q < 4; ++q) {
      b0[q] = *(const float4*)(w0p + k0 + q * 4);
      b1[q] = *(const float4*)(w1p + k0 + q * 4);
    }
    #pragma unroll
    for (int q = 0; q < 4; ++q) {
      #pragma unroll
      for (int r = 0; r < 8; ++r) {
        float4 a = *(const float4*)(hb + (size_t)r * H_DIM + k0 + q * 4); // uniform
        acc[r][0] = fmaf(a.x, b0[q].x, acc[r][0]);
        acc[r][0] = fmaf(a.y, b0[q].y, acc[r][0]);
        acc[r][0] = fmaf(a.z, b0[q].z, acc[r][0]);
        acc[r][0] = fmaf(a.w, b0[q].w, acc[r][0]);
        acc[r][1] = fmaf(a.x, b1[q].x, acc[r][1]);
        acc[r][1] = fmaf(a.y, b1[q].y, acc[r][1]);
        acc[r][1] = fmaf(a.z, b1[q].z, acc[r][1]);
        acc[r][1] = fmaf(a.w, b1[q].w, acc[r][1]);
      }
    }
  }

  const float fb0 = fcb[c0];
  const float fb1 = fcb[c0 + 1];
  #pragma unroll
  for (int r = 0; r < 8; ++r) {
    float z0 = acc[r][0] + fb0;
    float z1 = acc[r][1] + fb1;
    *(float2*)(out + (size_t)(r0 + r) * T * V_DIM + (size_t)t * V_DIM + c0)
        = make_float2(z0, z1);
    float v = z0; int ix = c0;
    if (z1 > v) { v = z1; ix = c0 + 1; }   // strict >: first index kept
    bv[r][tid] = v;
    bi[r][tid] = ix;
  }
  __syncthreads();

  #pragma unroll
  for (int rr = 0; rr < 2; ++rr) {
    int r = wv * 2 + rr;
    float best = bv[r][lane];
    int   bidx = bi[r][lane];
    #pragma unroll
    for (int s = 1; s < 4; ++s) {
      float ov = bv[r][lane + 64 * s];
      int   oi = bi[r][lane + 64 * s];
      if (ov > best || (ov == best && oi < bidx)) { best = ov; bidx = oi; }
    }
    #pragma unroll
    for (int off = 32; off; off >>= 1) {
      float ov = __shfl_xor(best, off);
      int   oi = __shfl_xor(bidx, off);
      if (ov > best || (ov == best && oi < bidx)) { best = ov; bidx = oi; }
    }
    if (lane == 0) tok[r0 + r] = bidx;
  }
}

extern "C" void kernel_launch(void* const* d_in, const int* in_sizes, int n_in,
                              void* d_out, int out_size, void* d_ws, size_t ws_size,
                              hipStream_t stream) {
  const int*   source  = (const int*)d_in[0];
  const float* enc_emb = (const float*)d_in[2];
  const float* enc_Wih = (const float*)d_in[3];
  const float* enc_Whh = (const float*)d_in[4];
  const float* enc_bih = (const float*)d_in[5];
  const float* enc_bhh = (const float*)d_in[6];
  const float* dec_emb = (const float*)d_in[7];
  const float* dec_Wih = (const float*)d_in[8];
  const float* dec_Whh = (const float*)d_in[9];
  const float* dec_bih = (const float*)d_in[10];
  const float* dec_bhh = (const float*)d_in[11];
  const float* fc_W    = (const float*)d_in[12];
  const float* fc_b    = (const float*)d_in[13];
  float* out = (float*)d_out;

  const int B = in_sizes[0] / S_LEN;              // 2048
  const int T = out_size / (B * V_DIM);           // 48

  const size_t BH = (size_t)B * H_DIM;
  const size_t WFSZ = (size_t)8 * W_TILES * TILE_SHORTS;   // shorts per set
  float* h0  = (float*)d_ws;
  float* h1  = h0 + BH;
  float* c   = h1 + BH;
  int*   tok = (int*)(c + BH);
  unsigned short* We = (unsigned short*)(tok + B);
  unsigned short* Wd = We + WFSZ;

  prep_weights<<<dim3(192 + 64), dim3(256), 0, stream>>>(
      enc_Wih, enc_Whh, dec_Wih, dec_Whh, We, Wd, h0, c, tok);

  dim3 blk(256);
  dim3 g_lstm(B / 64, H_DIM / 32);    // (32, 8) = 256 blocks
  dim3 g_declog(B / 8);               // 256 blocks

  const float* hin = h0;
  float* hout = h1;

  // ---- encoder ----
  for (int s = 0; s < S_LEN; ++s) {
    lstm_mfma_kernel<<<g_lstm, blk, 0, stream>>>(
        enc_emb, source, S_LEN, s, We, enc_bih, enc_bhh, hin, hout, c);
    const float* tmp = hout; hout = (float*)hin; hin = tmp;
  }

  // ---- decoder (greedy, autoregressive) ----
  for (int t = 0; t < T; ++t) {
    lstm_mfma_kernel<<<g_lstm, blk, 0, stream>>>(
        dec_emb, tok, 1, 0, Wd, dec_bih, dec_bhh, hin, hout, c);
    const float* tmp = hout; hout = (float*)hin; hin = tmp;
    declog_kernel<<<g_declog, blk, 0, stream>>>(hin, fc_W, fc_b, out, tok, t, T);
  }
}

// Round 15
// 2126.028 us; speedup vs baseline: 1.9012x; 1.1115x over previous
//
#include <hip/hip_runtime.h>
#include <cmath>

#define S_LEN 32
#define E_DIM 128
#define H_DIM 256
#define V_DIM 512
#define NTILE 18            // fp16 split: 0-5 a1w1, 6-11 a1w2s, 12-17 a2s*w1
#define W_TILES 12          // unique W tiles stored (tiles 12-17 reuse 0-5)
#define TILE_SHORTS 8192    // 16 frags x 64 lanes x 8 halfs = 16 KB
#define A_SHORTS 24576      // 12 ksub x 4 rowblk x 64 lanes x 8 = 48 KB

typedef _Float16 f16x8v __attribute__((ext_vector_type(8)));
typedef __attribute__((ext_vector_type(4))) float f32x4v;

#define SCALE_S 4096.0f          // 2^12
#define INV_S   2.44140625e-4f   // 2^-12 (exact)

__device__ __forceinline__ float sigf(float x) { return 1.0f / (1.0f + expf(-x)); }

// level-L fp16 component: x ~= h1 + h2*2^-12 + O(2^-22 x); h2 stored pre-scaled
template<int L>
__device__ __forceinline__ unsigned short lvl_f16(float x) {
  _Float16 h1 = (_Float16)x;                       // RNE
  if (L == 1) return __builtin_bit_cast(unsigned short, h1);
  _Float16 h2 = (_Float16)((x - (float)h1) * SCALE_S);
  return __builtin_bit_cast(unsigned short, h2);
}

// ---------------------------------------------------------------------------
// prep — EXACT round-14 version (fp16 2-level fragment stream + init tail).
// ---------------------------------------------------------------------------
__global__ void prep_weights(const float* __restrict__ eWih, const float* __restrict__ eWhh,
                             const float* __restrict__ dWih, const float* __restrict__ dWhh,
                             unsigned short* __restrict__ We, unsigned short* __restrict__ Wd,
                             float* __restrict__ h0, float* __restrict__ c,
                             int* __restrict__ tok)
{
  const int b = blockIdx.x;
  if (b >= 192) {                         // ---- init tail: 64 blocks
    const int pb = b - 192;
    const int gt = pb * 256 + threadIdx.x;     // 0..16383
    float4 z = make_float4(0.f, 0.f, 0.f, 0.f);
    float4* p0 = (float4*)h0;
    float4* pc = (float4*)c;
    for (int i = gt; i < 131072; i += 16384) { p0[i] = z; pc[i] = z; }
    if (gt < 2048) tok[gt] = 0;
    return;
  }
  const int j    = b % W_TILES;           // 0..11
  const int rest = b / W_TILES;
  const int nb   = rest & 7;
  const int set  = rest >> 3;
  const float* Wih = set ? dWih : eWih;
  const float* Whh = set ? dWhh : eWhh;
  unsigned short* dst = (set ? Wd : We) + ((size_t)nb * W_TILES + j) * TILE_SHORTS;
  const int lvl = (j < 6) ? 1 : 2;
  const int jj  = (j < 6) ? j : j - 6;

  for (int cpos = threadIdx.x; cpos < 1024; cpos += 256) {
    int fi = cpos >> 6, l = cpos & 63;
    int kh = fi >> 3, wc = (fi >> 2) & 1, g = fi & 3;
    int n  = g * H_DIM + nb * 32 + wc * 16 + (l & 15);
    int kk = jj * 64 + kh * 32 + (l >> 4) * 8;
    unsigned short o8[8];
    #pragma unroll
    for (int e = 0; e < 8; ++e) {
      int k = kk + e;
      float v = (k < E_DIM) ? Wih[(size_t)n * E_DIM + k]
                            : Whh[(size_t)n * H_DIM + (k - E_DIM)];
      o8[e] = (lvl == 1) ? lvl_f16<1>(v) : lvl_f16<2>(v);
    }
    uint4 pk;
    pk.x = (unsigned)o8[0] | ((unsigned)o8[1] << 16);
    pk.y = (unsigned)o8[2] | ((unsigned)o8[3] << 16);
    pk.z = (unsigned)o8[4] | ((unsigned)o8[5] << 16);
    pk.w = (unsigned)o8[6] | ((unsigned)o8[7] << 16);
    *(uint4*)&dst[(size_t)cpos * 8] = pk;
  }
}

// stage level-L fp16 of A=[emb[idx]|h_in] into fragment layout — EXACT r14 map
template<int L>
__device__ __forceinline__ void stage_A(unsigned short* Ax,
                                        const float* __restrict__ esrc,
                                        const float* __restrict__ hsrc,
                                        int arow, int q4) {
  const int rowblk = arow >> 4;
  const int rlo    = arow & 15;
  #pragma unroll
  for (int j = 0; j < 8; ++j) {
    int k0 = q4 * 4 + 16 * j;                 // 0..124
    float4 v = *(const float4*)(esrc + k0);
    unsigned short s0 = lvl_f16<L>(v.x), s1 = lvl_f16<L>(v.y),
                   s2 = lvl_f16<L>(v.z), s3 = lvl_f16<L>(v.w);
    uint2 p; p.x = (unsigned)s0 | ((unsigned)s1 << 16);
             p.y = (unsigned)s2 | ((unsigned)s3 << 16);
    int lane_w = rlo + ((k0 & 31) >> 3) * 16;
    *(uint2*)&Ax[(((k0 >> 5) * 4 + rowblk) * 64 + lane_w) * 8 + (k0 & 7)] = p;
  }
  #pragma unroll
  for (int j = 0; j < 16; ++j) {
    int k0 = q4 * 4 + 16 * j;                 // 0..252
    int kA = E_DIM + k0;
    float4 v = *(const float4*)(hsrc + k0);
    unsigned short s0 = lvl_f16<L>(v.x), s1 = lvl_f16<L>(v.y),
                   s2 = lvl_f16<L>(v.z), s3 = lvl_f16<L>(v.w);
    uint2 p; p.x = (unsigned)s0 | ((unsigned)s1 << 16);
             p.y = (unsigned)s2 | ((unsigned)s3 << 16);
    int lane_w = rlo + ((kA & 31) >> 3) * 16;
    *(uint2*)&Ax[(((kA >> 5) * 4 + rowblk) * 64 + lane_w) * 8 + (kA & 7)] = p;
  }
}

// ---------------------------------------------------------------------------
// LSTM step, fp16 2-level 3-term split — numerics IDENTICAL to round 14.
// NEW: B tiles stream L2 -> REGISTERS (per-lane coalesced uint4 loads from the
// fragment stream), 3 rotating named buffers, 2-tile prefetch. NO per-tile
// barriers (waves fully decoupled); only A-staging barriers (3/step).
// LDS = A only (48 KB).
// ---------------------------------------------------------------------------
__launch_bounds__(256)
__global__ void lstm_mfma_kernel(const float* __restrict__ emb,
                                 const int* __restrict__ idx_src, int idx_stride, int idx_off,
                                 const unsigned short* __restrict__ Wf,
                                 const float* __restrict__ bih, const float* __restrict__ bhh,
                                 const float* __restrict__ h_in,
                                 float* __restrict__ h_out, float* __restrict__ c)
{
  __shared__ __align__(16) unsigned short Ax[A_SHORTS];   // 48 KB

  const int tid  = threadIdx.x;
  const int lane = tid & 63;
  const int m0 = blockIdx.x * 64;
  const int nb = blockIdx.y;

  const int arow = tid >> 2;
  const int q4   = tid & 3;
  const int token = idx_src[(size_t)(m0 + arow) * idx_stride + idx_off];
  const float* esrc = emb + (size_t)token * E_DIM;
  const float* hsrc = h_in + (size_t)(m0 + arow) * H_DIM;

  const int wm = (tid >> 6) & 1;
  const int wc = tid >> 7;

  stage_A<1>(Ax, esrc, hsrc, arow, q4);
  __syncthreads();

  // per-wave B fragment base within a tile: frags (kh*8 + wc*4 + g), lane*8
  const unsigned short* wbase = Wf + (size_t)nb * (W_TILES * TILE_SHORTS)
                                   + (size_t)(wc * 4) * 512 + (size_t)lane * 8;

  f32x4v accA[2][4], accB[2][4];
  #pragma unroll
  for (int mf = 0; mf < 2; ++mf)
    #pragma unroll
    for (int g = 0; g < 4; ++g) {
      accA[mf][g] = (f32x4v){0.f, 0.f, 0.f, 0.f};
      accB[mf][g] = (f32x4v){0.f, 0.f, 0.f, 0.f};
    }

  uint4 pA[8], pB[8], pC[8];

#define LOADT(J, P)                                                            \
  {                                                                            \
    const unsigned short* bsrc =                                               \
        wbase + (size_t)(((J) < W_TILES) ? (J) : (J) - W_TILES) * TILE_SHORTS; \
    _Pragma("unroll")                                                          \
    for (int f = 0; f < 4; ++f) {                                              \
      P[f]     = *(const uint4*)(bsrc + (size_t)f * 512);                      \
      P[4 + f] = *(const uint4*)(bsrc + (size_t)(8 + f) * 512);                \
    }                                                                          \
  }

#define MFMAT(J, P, ACC)                                                       \
  {                                                                            \
    const int ks0 = ((J) % 6) * 2;                                             \
    _Pragma("unroll")                                                          \
    for (int kh = 0; kh < 2; ++kh) {                                           \
      f16x8v af0 = *(const f16x8v*)&Ax[((ks0 + kh) * 4 + wm * 2) * 512 + lane * 8];       \
      f16x8v af1 = *(const f16x8v*)&Ax[((ks0 + kh) * 4 + wm * 2 + 1) * 512 + lane * 8];   \
      _Pragma("unroll")                                                        \
      for (int g = 0; g < 4; ++g) {                                            \
        f16x8v bfr = __builtin_bit_cast(f16x8v, P[kh * 4 + g]);                \
        ACC[0][g] = __builtin_amdgcn_mfma_f32_16x16x32_f16(af0, bfr, ACC[0][g], 0, 0, 0); \
        ACC[1][g] = __builtin_amdgcn_mfma_f32_16x16x32_f16(af1, bfr, ACC[1][g], 0, 0, 0); \
      }                                                                        \
    }                                                                          \
  }

  LOADT(0, pA); LOADT(1, pB);

  LOADT(2, pC);  MFMAT(0, pA, accA);
  LOADT(3, pA);  MFMAT(1, pB, accA);
  LOADT(4, pB);  MFMAT(2, pC, accA);
  LOADT(5, pC);  MFMAT(3, pA, accA);
  LOADT(6, pA);  MFMAT(4, pB, accA);
  LOADT(7, pB);  MFMAT(5, pC, accA);
  LOADT(8, pC);  MFMAT(6, pA, accB);
  LOADT(9, pA);  MFMAT(7, pB, accB);
  LOADT(10, pB); MFMAT(8, pC, accB);
  LOADT(11, pC); MFMAT(9, pA, accB);
  LOADT(12, pA); MFMAT(10, pB, accB);
  LOADT(13, pB); MFMAT(11, pC, accB);

  // ---- A level switch: all waves done with lvl-1 A; restage lvl-2
  __syncthreads();
  stage_A<2>(Ax, esrc, hsrc, arow, q4);
  __syncthreads();

  LOADT(14, pC); MFMAT(12, pA, accB);
  LOADT(15, pA); MFMAT(13, pB, accB);
  LOADT(16, pB); MFMAT(14, pC, accB);
  LOADT(17, pC); MFMAT(15, pA, accB);
                 MFMAT(16, pB, accB);
                 MFMAT(17, pC, accB);

#undef LOADT
#undef MFMAT

  // ---- epilogue: combine scales, bias + cell update — EXACT round-14
  const int lr = tid & 15;
  const int l4 = lane >> 4;
  const int col = nb * 32 + wc * 16 + lr;
  float bs[4];
  #pragma unroll
  for (int g = 0; g < 4; ++g) bs[g] = bih[g * H_DIM + col] + bhh[g * H_DIM + col];

  #pragma unroll
  for (int mf = 0; mf < 2; ++mf) {
    #pragma unroll
    for (int r = 0; r < 4; ++r) {
      int row = m0 + wm * 32 + mf * 16 + l4 * 4 + r;
      float zi = fmaf(accB[mf][0][r], INV_S, accA[mf][0][r]) + bs[0];
      float zf = fmaf(accB[mf][1][r], INV_S, accA[mf][1][r]) + bs[1];
      float zg = fmaf(accB[mf][2][r], INV_S, accA[mf][2][r]) + bs[2];
      float zo = fmaf(accB[mf][3][r], INV_S, accA[mf][3][r]) + bs[3];
      float co = c[(size_t)row * H_DIM + col];
      float cn = sigf(zf) * co + sigf(zi) * tanhf(zg);
      c[(size_t)row * H_DIM + col] = cn;
      h_out[(size_t)row * H_DIM + col] = sigf(zo) * tanhf(cn);
    }
  }
}

// ---------------------------------------------------------------------------
// declog v4 — EXACT round-13/14 version (known-good, ~6 us).
// ---------------------------------------------------------------------------
__launch_bounds__(256)
__global__ void declog_kernel(const float* __restrict__ h,    // [B, H]
                              const float* __restrict__ fcW,  // [V, H]
                              const float* __restrict__ fcb,  // [V]
                              float* __restrict__ out,        // [B, T, V]
                              int* __restrict__ tok,          // [B]
                              int t, int T)
{
  __shared__ float bv[8][256];
  __shared__ int   bi[8][256];

  const int tid  = threadIdx.x;
  const int lane = tid & 63;
  const int wv   = tid >> 6;
  const int r0   = blockIdx.x * 8;
  const int c0   = tid * 2;             // this thread's 2 vocab cols

  const float* hb  = h + (size_t)r0 * H_DIM;
  const float* w0p = fcW + (size_t)c0 * H_DIM;
  const float* w1p = w0p + H_DIM;

  float acc[8][2] = {};                 // [row][col]

  #pragma unroll 1
  for (int k0 = 0; k0 < H_DIM; k0 += 16) {
    float4 b0[4], b1[4];
    #pragma unroll
    for (int q = 0; q < 4; ++q) {
      b0[q] = *(const float4*)(w0p + k0 + q * 4);
      b1[q] = *(const float4*)(w1p + k0 + q * 4);
    }
    #pragma unroll
    for (int q = 0; q < 4; ++q) {
      #pragma unroll
      for (int r = 0; r < 8; ++r) {
        float4 a = *(const float4*)(hb + (size_t)r * H_DIM + k0 + q * 4); // uniform
        acc[r][0] = fmaf(a.x, b0[q].x, acc[r][0]);
        acc[r][0] = fmaf(a.y, b0[q].y, acc[r][0]);
        acc[r][0] = fmaf(a.z, b0[q].z, acc[r][0]);
        acc[r][0] = fmaf(a.w, b0[q].w, acc[r][0]);
        acc[r][1] = fmaf(a.x, b1[q].x, acc[r][1]);
        acc[r][1] = fmaf(a.y, b1[q].y, acc[r][1]);
        acc[r][1] = fmaf(a.z, b1[q].z, acc[r][1]);
        acc[r][1] = fmaf(a.w, b1[q].w, acc[r][1]);
      }
    }
  }

  const float fb0 = fcb[c0];
  const float fb1 = fcb[c0 + 1];
  #pragma unroll
  for (int r = 0; r < 8; ++r) {
    float z0 = acc[r][0] + fb0;
    float z1 = acc[r][1] + fb1;
    *(float2*)(out + (size_t)(r0 + r) * T * V_DIM + (size_t)t * V_DIM + c0)
        = make_float2(z0, z1);
    float v = z0; int ix = c0;
    if (z1 > v) { v = z1; ix = c0 + 1; }   // strict >: first index kept
    bv[r][tid] = v;
    bi[r][tid] = ix;
  }
  __syncthreads();

  #pragma unroll
  for (int rr = 0; rr < 2; ++rr) {
    int r = wv * 2 + rr;
    float best = bv[r][lane];
    int   bidx = bi[r][lane];
    #pragma unroll
    for (int s = 1; s < 4; ++s) {
      float ov = bv[r][lane + 64 * s];
      int   oi = bi[r][lane + 64 * s];
      if (ov > best || (ov == best && oi < bidx)) { best = ov; bidx = oi; }
    }
    #pragma unroll
    for (int off = 32; off; off >>= 1) {
      float ov = __shfl_xor(best, off);
      int   oi = __shfl_xor(bidx, off);
      if (ov > best || (ov == best && oi < bidx)) { best = ov; bidx = oi; }
    }
    if (lane == 0) tok[r0 + r] = bidx;
  }
}

extern "C" void kernel_launch(void* const* d_in, const int* in_sizes, int n_in,
                              void* d_out, int out_size, void* d_ws, size_t ws_size,
                              hipStream_t stream) {
  const int*   source  = (const int*)d_in[0];
  const float* enc_emb = (const float*)d_in[2];
  const float* enc_Wih = (const float*)d_in[3];
  const float* enc_Whh = (const float*)d_in[4];
  const float* enc_bih = (const float*)d_in[5];
  const float* enc_bhh = (const float*)d_in[6];
  const float* dec_emb = (const float*)d_in[7];
  const float* dec_Wih = (const float*)d_in[8];
  const float* dec_Whh = (const float*)d_in[9];
  const float* dec_bih = (const float*)d_in[10];
  const float* dec_bhh = (const float*)d_in[11];
  const float* fc_W    = (const float*)d_in[12];
  const float* fc_b    = (const float*)d_in[13];
  float* out = (float*)d_out;

  const int B = in_sizes[0] / S_LEN;              // 2048
  const int T = out_size / (B * V_DIM);           // 48

  const size_t BH = (size_t)B * H_DIM;
  const size_t WFSZ = (size_t)8 * W_TILES * TILE_SHORTS;   // shorts per set
  float* h0  = (float*)d_ws;
  float* h1  = h0 + BH;
  float* c   = h1 + BH;
  int*   tok = (int*)(c + BH);
  unsigned short* We = (unsigned short*)(tok + B);
  unsigned short* Wd = We + WFSZ;

  prep_weights<<<dim3(192 + 64), dim3(256), 0, stream>>>(
      enc_Wih, enc_Whh, dec_Wih, dec_Whh, We, Wd, h0, c, tok);

  dim3 blk(256);
  dim3 g_lstm(B / 64, H_DIM / 32);    // (32, 8) = 256 blocks
  dim3 g_declog(B / 8);               // 256 blocks

  const float* hin = h0;
  float* hout = h1;

  // ---- encoder ----
  for (int s = 0; s < S_LEN; ++s) {
    lstm_mfma_kernel<<<g_lstm, blk, 0, stream>>>(
        enc_emb, source, S_LEN, s, We, enc_bih, enc_bhh, hin, hout, c);
    const float* tmp = hout; hout = (float*)hin; hin = tmp;
  }

  // ---- decoder (greedy, autoregressive) ----
  for (int t = 0; t < T; ++t) {
    lstm_mfma_kernel<<<g_lstm, blk, 0, stream>>>(
        dec_emb, tok, 1, 0, Wd, dec_bih, dec_bhh, hin, hout, c);
    const float* tmp = hout; hout = (float*)hin; hin = tmp;
    declog_kernel<<<g_declog, blk, 0, stream>>>(hin, fc_W, fc_b, out, tok, t, T);
  }
}

// Round 16
// 2019.900 us; speedup vs baseline: 2.0011x; 1.0525x over previous
//
#include <hip/hip_runtime.h>
#include <cmath>

#define S_LEN 32
#define E_DIM 128
#define H_DIM 256
#define V_DIM 512
#define NTILE 18            // fp16 split: 0-5 a1w1, 6-11 a1w2s, 12-17 a2s*w1
#define W_TILES 12          // unique W tiles stored (tiles 12-17 reuse 0-5)
#define TILE_SHORTS 8192    // 16 frags x 64 lanes x 8 halfs = 16 KB
#define A_SHORTS 24576      // 12 ksub x 4 rowblk x 64 lanes x 8 = 48 KB
#define ZPITCH 132          // z-buffer row pitch (words): 132&31=4 -> spread banks

typedef _Float16 f16x8v __attribute__((ext_vector_type(8)));
typedef __attribute__((ext_vector_type(4))) float f32x4v;

#define SCALE_S 4096.0f          // 2^12
#define INV_S   2.44140625e-4f   // 2^-12 (exact)

__device__ __forceinline__ float sigf(float x) { return 1.0f / (1.0f + expf(-x)); }

// level-L fp16 component: x ~= h1 + h2*2^-12 + O(2^-22 x); h2 stored pre-scaled
template<int L>
__device__ __forceinline__ unsigned short lvl_f16(float x) {
  _Float16 h1 = (_Float16)x;                       // RNE
  if (L == 1) return __builtin_bit_cast(unsigned short, h1);
  _Float16 h2 = (_Float16)((x - (float)h1) * SCALE_S);
  return __builtin_bit_cast(unsigned short, h2);
}

// ---------------------------------------------------------------------------
// prep — EXACT round-14/15 version (fp16 2-level fragment stream + init tail).
// ---------------------------------------------------------------------------
__global__ void prep_weights(const float* __restrict__ eWih, const float* __restrict__ eWhh,
                             const float* __restrict__ dWih, const float* __restrict__ dWhh,
                             unsigned short* __restrict__ We, unsigned short* __restrict__ Wd,
                             float* __restrict__ h0, float* __restrict__ c,
                             int* __restrict__ tok)
{
  const int b = blockIdx.x;
  if (b >= 192) {                         // ---- init tail: 64 blocks
    const int pb = b - 192;
    const int gt = pb * 256 + threadIdx.x;     // 0..16383
    float4 z = make_float4(0.f, 0.f, 0.f, 0.f);
    float4* p0 = (float4*)h0;
    float4* pc = (float4*)c;
    for (int i = gt; i < 131072; i += 16384) { p0[i] = z; pc[i] = z; }
    if (gt < 2048) tok[gt] = 0;
    return;
  }
  const int j    = b % W_TILES;           // 0..11
  const int rest = b / W_TILES;
  const int nb   = rest & 7;
  const int set  = rest >> 3;
  const float* Wih = set ? dWih : eWih;
  const float* Whh = set ? dWhh : eWhh;
  unsigned short* dst = (set ? Wd : We) + ((size_t)nb * W_TILES + j) * TILE_SHORTS;
  const int lvl = (j < 6) ? 1 : 2;
  const int jj  = (j < 6) ? j : j - 6;

  for (int cpos = threadIdx.x; cpos < 1024; cpos += 256) {
    int fi = cpos >> 6, l = cpos & 63;
    int kh = fi >> 3, wc = (fi >> 2) & 1, g = fi & 3;
    int n  = g * H_DIM + nb * 32 + wc * 16 + (l & 15);
    int kk = jj * 64 + kh * 32 + (l >> 4) * 8;
    unsigned short o8[8];
    #pragma unroll
    for (int e = 0; e < 8; ++e) {
      int k = kk + e;
      float v = (k < E_DIM) ? Wih[(size_t)n * E_DIM + k]
                            : Whh[(size_t)n * H_DIM + (k - E_DIM)];
      o8[e] = (lvl == 1) ? lvl_f16<1>(v) : lvl_f16<2>(v);
    }
    uint4 pk;
    pk.x = (unsigned)o8[0] | ((unsigned)o8[1] << 16);
    pk.y = (unsigned)o8[2] | ((unsigned)o8[3] << 16);
    pk.z = (unsigned)o8[4] | ((unsigned)o8[5] << 16);
    pk.w = (unsigned)o8[6] | ((unsigned)o8[7] << 16);
    *(uint4*)&dst[(size_t)cpos * 8] = pk;
  }
}

// stage BOTH fp16 levels of A=[emb[idx]|h_in] in one pass (same values as the
// separate stage_A<1>/<2> of rounds 14-15 -> bit-identical fragments).
__device__ __forceinline__ void stage_A12(unsigned short* Ax1, unsigned short* Ax2,
                                          const float* __restrict__ esrc,
                                          const float* __restrict__ hsrc,
                                          int arow, int q4) {
  const int rowblk = arow >> 4;
  const int rlo    = arow & 15;
  #pragma unroll
  for (int j = 0; j < 24; ++j) {
    int k0, kA;
    const float* src;
    if (j < 8) { k0 = q4 * 4 + 16 * j; kA = k0; src = esrc + k0; }
    else       { k0 = q4 * 4 + 16 * (j - 8); kA = E_DIM + k0; src = hsrc + k0; }
    float4 v = *(const float4*)src;
    _Float16 a1x = (_Float16)v.x, a1y = (_Float16)v.y,
             a1z = (_Float16)v.z, a1w = (_Float16)v.w;
    _Float16 a2x = (_Float16)((v.x - (float)a1x) * SCALE_S);
    _Float16 a2y = (_Float16)((v.y - (float)a1y) * SCALE_S);
    _Float16 a2z = (_Float16)((v.z - (float)a1z) * SCALE_S);
    _Float16 a2w = (_Float16)((v.w - (float)a1w) * SCALE_S);
    int lane_w = rlo + ((kA & 31) >> 3) * 16;
    int idx = (((kA >> 5) * 4 + rowblk) * 64 + lane_w) * 8 + (kA & 7);
    uint2 p1, p2;
    p1.x = (unsigned)__builtin_bit_cast(unsigned short, a1x)
         | ((unsigned)__builtin_bit_cast(unsigned short, a1y) << 16);
    p1.y = (unsigned)__builtin_bit_cast(unsigned short, a1z)
         | ((unsigned)__builtin_bit_cast(unsigned short, a1w) << 16);
    p2.x = (unsigned)__builtin_bit_cast(unsigned short, a2x)
         | ((unsigned)__builtin_bit_cast(unsigned short, a2y) << 16);
    p2.y = (unsigned)__builtin_bit_cast(unsigned short, a2z)
         | ((unsigned)__builtin_bit_cast(unsigned short, a2w) << 16);
    *(uint2*)&Ax1[idx] = p1;
    *(uint2*)&Ax2[idx] = p2;
  }
}

// ---------------------------------------------------------------------------
// LSTM step, fp16 2-level 3-term split — numerics IDENTICAL to rounds 14-15.
// NEW vs r15: (1) both A levels staged upfront (no mid-loop barriers/restage);
// (2) epilogue transposed through LDS z-buffer -> coalesced float4 c/h I/O;
// (3) B tiles 0/1 issued before A staging; c prefetched under last MFMAs.
// LDS = 2 x 48 KB A levels (z-buffer reuses Ax1 region).
// ---------------------------------------------------------------------------
__launch_bounds__(256)
__global__ void lstm_mfma_kernel(const float* __restrict__ emb,
                                 const int* __restrict__ idx_src, int idx_stride, int idx_off,
                                 const unsigned short* __restrict__ Wf,
                                 const float* __restrict__ bih, const float* __restrict__ bhh,
                                 const float* __restrict__ h_in,
                                 float* __restrict__ h_out, float* __restrict__ c)
{
  __shared__ __align__(16) unsigned short Ax1[A_SHORTS];   // 48 KB (z-buffer alias)
  __shared__ __align__(16) unsigned short Ax2[A_SHORTS];   // 48 KB

  const int tid  = threadIdx.x;
  const int lane = tid & 63;
  const int m0 = blockIdx.x * 64;
  const int nb = blockIdx.y;
  const int nc0 = nb * 32;

  const int arow = tid >> 2;
  const int q4   = tid & 3;
  const int token = idx_src[(size_t)(m0 + arow) * idx_stride + idx_off];
  const float* esrc = emb + (size_t)token * E_DIM;
  const float* hsrc = h_in + (size_t)(m0 + arow) * H_DIM;

  const int wm = (tid >> 6) & 1;
  const int wc = tid >> 7;
  const int lr = tid & 15;
  const int l4 = lane >> 4;

  // per-wave B fragment base within a tile: frags (kh*8 + wc*4 + g), lane*8
  const unsigned short* wbase = Wf + (size_t)nb * (W_TILES * TILE_SHORTS)
                                   + (size_t)(wc * 4) * 512 + (size_t)lane * 8;

  f32x4v accA[2][4], accB[2][4];
  #pragma unroll
  for (int mf = 0; mf < 2; ++mf)
    #pragma unroll
    for (int g = 0; g < 4; ++g) {
      accA[mf][g] = (f32x4v){0.f, 0.f, 0.f, 0.f};
      accB[mf][g] = (f32x4v){0.f, 0.f, 0.f, 0.f};
    }

  uint4 pA[8], pB[8], pC[8];

#define LOADT(J, P)                                                            \
  {                                                                            \
    const unsigned short* bsrc =                                               \
        wbase + (size_t)(((J) < W_TILES) ? (J) : (J) - W_TILES) * TILE_SHORTS; \
    _Pragma("unroll")                                                          \
    for (int f = 0; f < 4; ++f) {                                              \
      P[f]     = *(const uint4*)(bsrc + (size_t)f * 512);                      \
      P[4 + f] = *(const uint4*)(bsrc + (size_t)(8 + f) * 512);                \
    }                                                                          \
  }

#define MFMAT(J, P, ACC, AXB)                                                  \
  {                                                                            \
    const int ks0 = ((J) % 6) * 2;                                             \
    _Pragma("unroll")                                                          \
    for (int kh = 0; kh < 2; ++kh) {                                           \
      f16x8v af0 = *(const f16x8v*)&AXB[((ks0 + kh) * 4 + wm * 2) * 512 + lane * 8];      \
      f16x8v af1 = *(const f16x8v*)&AXB[((ks0 + kh) * 4 + wm * 2 + 1) * 512 + lane * 8];  \
      _Pragma("unroll")                                                        \
      for (int g = 0; g < 4; ++g) {                                            \
        f16x8v bfr = __builtin_bit_cast(f16x8v, P[kh * 4 + g]);                \
        ACC[0][g] = __builtin_amdgcn_mfma_f32_16x16x32_f16(af0, bfr, ACC[0][g], 0, 0, 0); \
        ACC[1][g] = __builtin_amdgcn_mfma_f32_16x16x32_f16(af1, bfr, ACC[1][g], 0, 0, 0); \
      }                                                                        \
    }                                                                          \
  }

  // issue first B tiles BEFORE A staging (their L2 latency hides under cvt work)
  LOADT(0, pA); LOADT(1, pB);

  stage_A12(Ax1, Ax2, esrc, hsrc, arow, q4);
  asm volatile("s_waitcnt lgkmcnt(0)" ::: "memory");   // A writes visible
  __builtin_amdgcn_s_barrier();                        // B loads stay in flight

  LOADT(2, pC);  MFMAT(0, pA, accA, Ax1);
  LOADT(3, pA);  MFMAT(1, pB, accA, Ax1);
  LOADT(4, pB);  MFMAT(2, pC, accA, Ax1);
  LOADT(5, pC);  MFMAT(3, pA, accA, Ax1);
  LOADT(6, pA);  MFMAT(4, pB, accA, Ax1);
  LOADT(7, pB);  MFMAT(5, pC, accA, Ax1);
  LOADT(8, pC);  MFMAT(6, pA, accB, Ax1);
  LOADT(9, pA);  MFMAT(7, pB, accB, Ax1);
  LOADT(10, pB); MFMAT(8, pC, accB, Ax1);
  LOADT(11, pC); MFMAT(9, pA, accB, Ax1);
  LOADT(12, pA); MFMAT(10, pB, accB, Ax1);
  LOADT(13, pB); MFMAT(11, pC, accB, Ax1);
  LOADT(14, pC); MFMAT(12, pA, accB, Ax2);
  LOADT(15, pA); MFMAT(13, pB, accB, Ax2);
  LOADT(16, pB); MFMAT(14, pC, accB, Ax2);
  LOADT(17, pC);

  // ---- reader-phase indices + c prefetch (covered by the last 3 MFMA tiles)
  const int er  = tid >> 2;              // local row 0..63
  const int ec4 = (tid & 3) * 2;         // local float4-col {0,2,4,6}
  const float* cp0 = c + (size_t)(m0 + er) * H_DIM + nc0 + ec4 * 4;
  float4 cold0 = *(const float4*)(cp0);
  float4 cold1 = *(const float4*)(cp0 + 4);

  MFMAT(15, pA, accB, Ax2);
  MFMAT(16, pB, accB, Ax2);
  MFMAT(17, pC, accB, Ax2);

#undef LOADT
#undef MFMAT

  // ---- epilogue stage 1: combine scales + bias -> z LDS buffer (reuse Ax1)
  float bs[4];
  #pragma unroll
  for (int g = 0; g < 4; ++g)
    bs[g] = bih[g * H_DIM + nc0 + wc * 16 + lr] + bhh[g * H_DIM + nc0 + wc * 16 + lr];

  float* zb = (float*)Ax1;
  asm volatile("s_waitcnt lgkmcnt(0)" ::: "memory");
  __builtin_amdgcn_s_barrier();          // all waves done reading Ax1/Ax2

  #pragma unroll
  for (int mf = 0; mf < 2; ++mf)
    #pragma unroll
    for (int r = 0; r < 4; ++r) {
      int row_l = wm * 32 + mf * 16 + l4 * 4 + r;
      int base = row_l * ZPITCH + (wc * 16 + lr) * 4;
      #pragma unroll
      for (int g = 0; g < 4; ++g)
        zb[base + g] = fmaf(accB[mf][g][r], INV_S, accA[mf][g][r]) + bs[g];
    }

  asm volatile("s_waitcnt lgkmcnt(0)" ::: "memory");
  __builtin_amdgcn_s_barrier();          // z visible

  // ---- epilogue stage 2: cell update, coalesced float4 c/h I/O
  {
    float* hp = h_out + (size_t)(m0 + er) * H_DIM + nc0 + ec4 * 4;
    float* cpw = (float*)cp0;
    #pragma unroll
    for (int s = 0; s < 2; ++s) {
      int c4 = ec4 + s;
      float4 cold = s ? cold1 : cold0;
      float cov[4] = {cold.x, cold.y, cold.z, cold.w};
      float cnv[4], hnv[4];
      #pragma unroll
      for (int j = 0; j < 4; ++j) {
        float4 zq = *(const float4*)&zb[er * ZPITCH + c4 * 16 + j * 4];
        float zi = zq.x, zf = zq.y, zg = zq.z, zo = zq.w;
        float cn = sigf(zf) * cov[j] + sigf(zi) * tanhf(zg);
        cnv[j] = cn;
        hnv[j] = sigf(zo) * tanhf(cn);
      }
      *(float4*)(cpw + s * 4) = make_float4(cnv[0], cnv[1], cnv[2], cnv[3]);
      *(float4*)(hp + s * 4)  = make_float4(hnv[0], hnv[1], hnv[2], hnv[3]);
    }
  }
}

// ---------------------------------------------------------------------------
// declog v4 — EXACT round-13/14/15 version (known-good, ~6 us).
// ---------------------------------------------------------------------------
__launch_bounds__(256)
__global__ void declog_kernel(const float* __restrict__ h,    // [B, H]
                              const float* __restrict__ fcW,  // [V, H]
                              const float* __restrict__ fcb,  // [V]
                              float* __restrict__ out,        // [B, T, V]
                              int* __restrict__ tok,          // [B]
                              int t, int T)
{
  __shared__ float bv[8][256];
  __shared__ int   bi[8][256];

  const int tid  = threadIdx.x;
  const int lane = tid & 63;
  const int wv   = tid >> 6;
  const int r0   = blockIdx.x * 8;
  const int c0   = tid * 2;             // this thread's 2 vocab cols

  const float* hb  = h + (size_t)r0 * H_DIM;
  const float* w0p = fcW + (size_t)c0 * H_DIM;
  const float* w1p = w0p + H_DIM;

  float acc[8][2] = {};                 // [row][col]

  #pragma unroll 1
  for (int k0 = 0; k0 < H_DIM; k0 += 16) {
    float4 b0[4], b1[4];
    #pragma unroll
    for (int q = 0; q < 4; ++q) {
      b0[q] = *(const float4*)(w0p + k0 + q * 4);
      b1[q] = *(const float4*)(w1p + k0 + q * 4);
    }
    #pragma unroll
    for (int q = 0; q < 4; ++q) {
      #pragma unroll
      for (int r = 0; r < 8; ++r) {
        float4 a = *(const float4*)(hb + (size_t)r * H_DIM + k0 + q * 4); // uniform
        acc[r][0] = fmaf(a.x, b0[q].x, acc[r][0]);
        acc[r][0] = fmaf(a.y, b0[q].y, acc[r][0]);
        acc[r][0] = fmaf(a.z, b0[q].z, acc[r][0]);
        acc[r][0] = fmaf(a.w, b0[q].w, acc[r][0]);
        acc[r][1] = fmaf(a.x, b1[q].x, acc[r][1]);
        acc[r][1] = fmaf(a.y, b1[q].y, acc[r][1]);
        acc[r][1] = fmaf(a.z, b1[q].z, acc[r][1]);
        acc[r][1] = fmaf(a.w, b1[q].w, acc[r][1]);
      }
    }
  }

  const float fb0 = fcb[c0];
  const float fb1 = fcb[c0 + 1];
  #pragma unroll
  for (int r = 0; r < 8; ++r) {
    float z0 = acc[r][0] + fb0;
    float z1 = acc[r][1] + fb1;
    *(float2*)(out + (size_t)(r0 + r) * T * V_DIM + (size_t)t * V_DIM + c0)
        = make_float2(z0, z1);
    float v = z0; int ix = c0;
    if (z1 > v) { v = z1; ix = c0 + 1; }   // strict >: first index kept
    bv[r][tid] = v;
    bi[r][tid] = ix;
  }
  __syncthreads();

  #pragma unroll
  for (int rr = 0; rr < 2; ++rr) {
    int r = wv * 2 + rr;
    float best = bv[r][lane];
    int   bidx = bi[r][lane];
    #pragma unroll
    for (int s = 1; s < 4; ++s) {
      float ov = bv[r][lane + 64 * s];
      int   oi = bi[r][lane + 64 * s];
      if (ov > best || (ov == best && oi < bidx)) { best = ov; bidx = oi; }
    }
    #pragma unroll
    for (int off = 32; off; off >>= 1) {
      float ov = __shfl_xor(best, off);
      int   oi = __shfl_xor(bidx, off);
      if (ov > best || (ov == best && oi < bidx)) { best = ov; bidx = oi; }
    }
    if (lane == 0) tok[r0 + r] = bidx;
  }
}

extern "C" void kernel_launch(void* const* d_in, const int* in_sizes, int n_in,
                              void* d_out, int out_size, void* d_ws, size_t ws_size,
                              hipStream_t stream) {
  const int*   source  = (const int*)d_in[0];
  const float* enc_emb = (const float*)d_in[2];
  const float* enc_Wih = (const float*)d_in[3];
  const float* enc_Whh = (const float*)d_in[4];
  const float* enc_bih = (const float*)d_in[5];
  const float* enc_bhh = (const float*)d_in[6];
  const float* dec_emb = (const float*)d_in[7];
  const float* dec_Wih = (const float*)d_in[8];
  const float* dec_Whh = (const float*)d_in[9];
  const float* dec_bih = (const float*)d_in[10];
  const float* dec_bhh = (const float*)d_in[11];
  const float* fc_W    = (const float*)d_in[12];
  const float* fc_b    = (const float*)d_in[13];
  float* out = (float*)d_out;

  const int B = in_sizes[0] / S_LEN;              // 2048
  const int T = out_size / (B * V_DIM);           // 48

  const size_t BH = (size_t)B * H_DIM;
  const size_t WFSZ = (size_t)8 * W_TILES * TILE_SHORTS;   // shorts per set
  float* h0  = (float*)d_ws;
  float* h1  = h0 + BH;
  float* c   = h1 + BH;
  int*   tok = (int*)(c + BH);
  unsigned short* We = (unsigned short*)(tok + B);
  unsigned short* Wd = We + WFSZ;

  prep_weights<<<dim3(192 + 64), dim3(256), 0, stream>>>(
      enc_Wih, enc_Whh, dec_Wih, dec_Whh, We, Wd, h0, c, tok);

  dim3 blk(256);
  dim3 g_lstm(B / 64, H_DIM / 32);    // (32, 8) = 256 blocks
  dim3 g_declog(B / 8);               // 256 blocks

  const float* hin = h0;
  float* hout = h1;

  // ---- encoder ----
  for (int s = 0; s < S_LEN; ++s) {
    lstm_mfma_kernel<<<g_lstm, blk, 0, stream>>>(
        enc_emb, source, S_LEN, s, We, enc_bih, enc_bhh, hin, hout, c);
    const float* tmp = hout; hout = (float*)hin; hin = tmp;
  }

  // ---- decoder (greedy, autoregressive) ----
  for (int t = 0; t < T; ++t) {
    lstm_mfma_kernel<<<g_lstm, blk, 0, stream>>>(
        dec_emb, tok, 1, 0, Wd, dec_bih, dec_bhh, hin, hout, c);
    const float* tmp = hout; hout = (float*)hin; hin = tmp;
    declog_kernel<<<g_declog, blk, 0, stream>>>(hin, fc_W, fc_b, out, tok, t, T);
  }
}

// Round 17
// 1979.840 us; speedup vs baseline: 2.0416x; 1.0202x over previous
//
#include <hip/hip_runtime.h>
#include <cmath>

#define S_LEN 32
#define E_DIM 128
#define H_DIM 256
#define V_DIM 512
#define NTILE 18            // fp16 split: 0-5 a1w1, 6-11 a1w2s, 12-17 a2s*w1
#define W_TILES 12          // unique W tiles stored (tiles 12-17 reuse 0-5)
#define TILE_SHORTS 8192    // 16 frags x 64 lanes x 8 halfs = 16 KB
#define A_SHORTS 12288      // 12 ksub x 2 rowblk x 64 lanes x 8 = 24 KB
#define ZPITCH 132          // z-buffer row pitch (words)

typedef _Float16 f16x8v __attribute__((ext_vector_type(8)));
typedef __attribute__((ext_vector_type(4))) float f32x4v;

#define SCALE_S 4096.0f          // 2^12
#define INV_S   2.44140625e-4f   // 2^-12 (exact)

__device__ __forceinline__ float sigf(float x) { return 1.0f / (1.0f + expf(-x)); }

// level-L fp16 component: x ~= h1 + h2*2^-12 + O(2^-22 x); h2 stored pre-scaled
template<int L>
__device__ __forceinline__ unsigned short lvl_f16(float x) {
  _Float16 h1 = (_Float16)x;                       // RNE
  if (L == 1) return __builtin_bit_cast(unsigned short, h1);
  _Float16 h2 = (_Float16)((x - (float)h1) * SCALE_S);
  return __builtin_bit_cast(unsigned short, h2);
}

// ---------------------------------------------------------------------------
// prep — EXACT rounds 14-16 version (fp16 2-level fragment stream + init tail).
// (B fragment stream is independent of the M-tiling -> unchanged.)
// ---------------------------------------------------------------------------
__global__ void prep_weights(const float* __restrict__ eWih, const float* __restrict__ eWhh,
                             const float* __restrict__ dWih, const float* __restrict__ dWhh,
                             unsigned short* __restrict__ We, unsigned short* __restrict__ Wd,
                             float* __restrict__ h0, float* __restrict__ c,
                             int* __restrict__ tok)
{
  const int b = blockIdx.x;
  if (b >= 192) {                         // ---- init tail: 64 blocks
    const int pb = b - 192;
    const int gt = pb * 256 + threadIdx.x;     // 0..16383
    float4 z = make_float4(0.f, 0.f, 0.f, 0.f);
    float4* p0 = (float4*)h0;
    float4* pc = (float4*)c;
    for (int i = gt; i < 131072; i += 16384) { p0[i] = z; pc[i] = z; }
    if (gt < 2048) tok[gt] = 0;
    return;
  }
  const int j    = b % W_TILES;           // 0..11
  const int rest = b / W_TILES;
  const int nb   = rest & 7;
  const int set  = rest >> 3;
  const float* Wih = set ? dWih : eWih;
  const float* Whh = set ? dWhh : eWhh;
  unsigned short* dst = (set ? Wd : We) + ((size_t)nb * W_TILES + j) * TILE_SHORTS;
  const int lvl = (j < 6) ? 1 : 2;
  const int jj  = (j < 6) ? j : j - 6;

  for (int cpos = threadIdx.x; cpos < 1024; cpos += 256) {
    int fi = cpos >> 6, l = cpos & 63;
    int kh = fi >> 3, wc = (fi >> 2) & 1, g = fi & 3;
    int n  = g * H_DIM + nb * 32 + wc * 16 + (l & 15);
    int kk = jj * 64 + kh * 32 + (l >> 4) * 8;
    unsigned short o8[8];
    #pragma unroll
    for (int e = 0; e < 8; ++e) {
      int k = kk + e;
      float v = (k < E_DIM) ? Wih[(size_t)n * E_DIM + k]
                            : Whh[(size_t)n * H_DIM + (k - E_DIM)];
      o8[e] = (lvl == 1) ? lvl_f16<1>(v) : lvl_f16<2>(v);
    }
    uint4 pk;
    pk.x = (unsigned)o8[0] | ((unsigned)o8[1] << 16);
    pk.y = (unsigned)o8[2] | ((unsigned)o8[3] << 16);
    pk.z = (unsigned)o8[4] | ((unsigned)o8[5] << 16);
    pk.w = (unsigned)o8[6] | ((unsigned)o8[7] << 16);
    *(uint4*)&dst[(size_t)cpos * 8] = pk;
  }
}

// stage BOTH fp16 levels of A=[emb[idx]|h_in] (32 rows, 8 threads/row).
// Same per-element values as rounds 14-16 -> bit-identical fragments.
__device__ __forceinline__ void stage_A12(unsigned short* Ax1, unsigned short* Ax2,
                                          const float* __restrict__ esrc,
                                          const float* __restrict__ hsrc,
                                          int arow, int q8) {
  const int rowblk = arow >> 4;           // 0..1
  const int rlo    = arow & 15;
  #pragma unroll
  for (int j = 0; j < 12; ++j) {
    int k0, kA;
    const float* src;
    if (j < 4) { kA = q8 * 4 + 32 * j;            src = esrc + kA; }
    else       { k0 = q8 * 4 + 32 * (j - 4); kA = E_DIM + k0; src = hsrc + k0; }
    float4 v = *(const float4*)src;
    _Float16 a1x = (_Float16)v.x, a1y = (_Float16)v.y,
             a1z = (_Float16)v.z, a1w = (_Float16)v.w;
    _Float16 a2x = (_Float16)((v.x - (float)a1x) * SCALE_S);
    _Float16 a2y = (_Float16)((v.y - (float)a1y) * SCALE_S);
    _Float16 a2z = (_Float16)((v.z - (float)a1z) * SCALE_S);
    _Float16 a2w = (_Float16)((v.w - (float)a1w) * SCALE_S);
    int lane_w = rlo + ((kA & 31) >> 3) * 16;
    int idx = (((kA >> 5) * 2 + rowblk) * 64 + lane_w) * 8 + (kA & 7);
    uint2 p1, p2;
    p1.x = (unsigned)__builtin_bit_cast(unsigned short, a1x)
         | ((unsigned)__builtin_bit_cast(unsigned short, a1y) << 16);
    p1.y = (unsigned)__builtin_bit_cast(unsigned short, a1z)
         | ((unsigned)__builtin_bit_cast(unsigned short, a1w) << 16);
    p2.x = (unsigned)__builtin_bit_cast(unsigned short, a2x)
         | ((unsigned)__builtin_bit_cast(unsigned short, a2y) << 16);
    p2.y = (unsigned)__builtin_bit_cast(unsigned short, a2z)
         | ((unsigned)__builtin_bit_cast(unsigned short, a2w) << 16);
    *(uint2*)&Ax1[idx] = p1;
    *(uint2*)&Ax2[idx] = p2;
  }
}

// ---------------------------------------------------------------------------
// LSTM step, fp16 2-level 3-term split — numerics IDENTICAL to rounds 14-16.
// NEW vs r16: 32-row blocks, grid (64,8)=512, LDS 48 KB -> 2 blocks/CU
// (2 waves/SIMD TLP); B prefetch deepened to 4 buffers / 3-tile lookahead.
// ---------------------------------------------------------------------------
__launch_bounds__(256, 2)
__global__ void lstm_mfma_kernel(const float* __restrict__ emb,
                                 const int* __restrict__ idx_src, int idx_stride, int idx_off,
                                 const unsigned short* __restrict__ Wf,
                                 const float* __restrict__ bih, const float* __restrict__ bhh,
                                 const float* __restrict__ h_in,
                                 float* __restrict__ h_out, float* __restrict__ c)
{
  __shared__ __align__(16) unsigned short Ax1[A_SHORTS];   // 24 KB (z-buffer alias)
  __shared__ __align__(16) unsigned short Ax2[A_SHORTS];   // 24 KB

  const int tid  = threadIdx.x;
  const int lane = tid & 63;
  const int m0 = blockIdx.x * 32;
  const int nb = blockIdx.y;
  const int nc0 = nb * 32;

  const int arow = tid >> 3;        // 0..31
  const int q8   = tid & 7;
  const int token = idx_src[(size_t)(m0 + arow) * idx_stride + idx_off];
  const float* esrc = emb + (size_t)token * E_DIM;
  const float* hsrc = h_in + (size_t)(m0 + arow) * H_DIM;

  const int wm = (tid >> 6) & 1;
  const int wc = tid >> 7;
  const int lr = tid & 15;
  const int l4 = lane >> 4;

  // per-wave B fragment base within a tile: frags (kh*8 + wc*4 + g), lane*8
  const unsigned short* wbase = Wf + (size_t)nb * (W_TILES * TILE_SHORTS)
                                   + (size_t)(wc * 4) * 512 + (size_t)lane * 8;

  f32x4v accA[4], accB[4];
  #pragma unroll
  for (int g = 0; g < 4; ++g) {
    accA[g] = (f32x4v){0.f, 0.f, 0.f, 0.f};
    accB[g] = (f32x4v){0.f, 0.f, 0.f, 0.f};
  }

  uint4 pA[8], pB[8], pC[8], pD[8];

#define LOADT(J, P)                                                            \
  {                                                                            \
    const unsigned short* bsrc =                                               \
        wbase + (size_t)(((J) < W_TILES) ? (J) : (J) - W_TILES) * TILE_SHORTS; \
    _Pragma("unroll")                                                          \
    for (int f = 0; f < 4; ++f) {                                              \
      P[f]     = *(const uint4*)(bsrc + (size_t)f * 512);                      \
      P[4 + f] = *(const uint4*)(bsrc + (size_t)(8 + f) * 512);                \
    }                                                                          \
  }

#define MFMAT(J, P, ACC, AXB)                                                  \
  {                                                                            \
    const int ks0 = ((J) % 6) * 2;                                             \
    _Pragma("unroll")                                                          \
    for (int kh = 0; kh < 2; ++kh) {                                           \
      f16x8v af = *(const f16x8v*)&AXB[((ks0 + kh) * 2 + wm) * 512 + lane * 8]; \
      _Pragma("unroll")                                                        \
      for (int g = 0; g < 4; ++g) {                                            \
        f16x8v bfr = __builtin_bit_cast(f16x8v, P[kh * 4 + g]);                \
        ACC[g] = __builtin_amdgcn_mfma_f32_16x16x32_f16(af, bfr, ACC[g], 0, 0, 0); \
      }                                                                        \
    }                                                                          \
  }

  // issue first B tiles BEFORE A staging (their L2 latency hides under cvt work)
  LOADT(0, pA); LOADT(1, pB); LOADT(2, pC);

  stage_A12(Ax1, Ax2, esrc, hsrc, arow, q8);
  asm volatile("s_waitcnt lgkmcnt(0)" ::: "memory");   // A writes visible
  __builtin_amdgcn_s_barrier();                        // B loads stay in flight

  LOADT(3, pD);  MFMAT(0, pA, accA, Ax1);
  LOADT(4, pA);  MFMAT(1, pB, accA, Ax1);
  LOADT(5, pB);  MFMAT(2, pC, accA, Ax1);
  LOADT(6, pC);  MFMAT(3, pD, accA, Ax1);
  LOADT(7, pD);  MFMAT(4, pA, accA, Ax1);
  LOADT(8, pA);  MFMAT(5, pB, accA, Ax1);
  LOADT(9, pB);  MFMAT(6, pC, accB, Ax1);
  LOADT(10, pC); MFMAT(7, pD, accB, Ax1);
  LOADT(11, pD); MFMAT(8, pA, accB, Ax1);
  LOADT(12, pA); MFMAT(9, pB, accB, Ax1);
  LOADT(13, pB); MFMAT(10, pC, accB, Ax1);
  LOADT(14, pC); MFMAT(11, pD, accB, Ax1);
  LOADT(15, pD); MFMAT(12, pA, accB, Ax2);
  LOADT(16, pA); MFMAT(13, pB, accB, Ax2);
  LOADT(17, pB); MFMAT(14, pC, accB, Ax2);

  // ---- reader-phase indices + c prefetch (covered by the last 3 MFMA tiles)
  const int er = tid >> 3;               // local row 0..31
  const int ec = tid & 7;                // float4-col 0..7
  const float* cp0 = c + (size_t)(m0 + er) * H_DIM + nc0 + ec * 4;
  float4 cold = *(const float4*)(cp0);

  MFMAT(15, pD, accB, Ax2);
  MFMAT(16, pA, accB, Ax2);
  MFMAT(17, pB, accB, Ax2);

#undef LOADT
#undef MFMAT

  // ---- epilogue stage 1: combine scales + bias -> z LDS buffer (reuse Ax1)
  float bs[4];
  #pragma unroll
  for (int g = 0; g < 4; ++g)
    bs[g] = bih[g * H_DIM + nc0 + wc * 16 + lr] + bhh[g * H_DIM + nc0 + wc * 16 + lr];

  float* zb = (float*)Ax1;
  asm volatile("s_waitcnt lgkmcnt(0)" ::: "memory");
  __builtin_amdgcn_s_barrier();          // all waves done reading Ax1/Ax2

  #pragma unroll
  for (int r = 0; r < 4; ++r) {
    int row_l = wm * 16 + l4 * 4 + r;
    int base = row_l * ZPITCH + (wc * 16 + lr) * 4;
    #pragma unroll
    for (int g = 0; g < 4; ++g)
      zb[base + g] = fmaf(accB[g][r], INV_S, accA[g][r]) + bs[g];
  }

  asm volatile("s_waitcnt lgkmcnt(0)" ::: "memory");
  __builtin_amdgcn_s_barrier();          // z visible

  // ---- epilogue stage 2: cell update, coalesced float4 c/h I/O
  {
    float* hp  = h_out + (size_t)(m0 + er) * H_DIM + nc0 + ec * 4;
    float* cpw = (float*)cp0;
    float cov[4] = {cold.x, cold.y, cold.z, cold.w};
    float cnv[4], hnv[4];
    #pragma unroll
    for (int cc = 0; cc < 4; ++cc) {
      float4 zq = *(const float4*)&zb[er * ZPITCH + (ec * 4 + cc) * 4];
      float zi = zq.x, zf = zq.y, zg = zq.z, zo = zq.w;
      float cn = sigf(zf) * cov[cc] + sigf(zi) * tanhf(zg);
      cnv[cc] = cn;
      hnv[cc] = sigf(zo) * tanhf(cn);
    }
    *(float4*)cpw = make_float4(cnv[0], cnv[1], cnv[2], cnv[3]);
    *(float4*)hp  = make_float4(hnv[0], hnv[1], hnv[2], hnv[3]);
  }
}

// ---------------------------------------------------------------------------
// declog v4 — EXACT rounds 13-16 version (known-good, ~6 us).
// ---------------------------------------------------------------------------
__launch_bounds__(256)
__global__ void declog_kernel(const float* __restrict__ h,    // [B, H]
                              const float* __restrict__ fcW,  // [V, H]
                              const float* __restrict__ fcb,  // [V]
                              float* __restrict__ out,        // [B, T, V]
                              int* __restrict__ tok,          // [B]
                              int t, int T)
{
  __shared__ float bv[8][256];
  __shared__ int   bi[8][256];

  const int tid  = threadIdx.x;
  const int lane = tid & 63;
  const int wv   = tid >> 6;
  const int r0   = blockIdx.x * 8;
  const int c0   = tid * 2;             // this thread's 2 vocab cols

  const float* hb  = h + (size_t)r0 * H_DIM;
  const float* w0p = fcW + (size_t)c0 * H_DIM;
  const float* w1p = w0p + H_DIM;

  float acc[8][2] = {};                 // [row][col]

  #pragma unroll 1
  for (int k0 = 0; k0 < H_DIM; k0 += 16) {
    float4 b0[4], b1[4];
    #pragma unroll
    for (int q = 0; q < 4; ++q) {
      b0[q] = *(const float4*)(w0p + k0 + q * 4);
      b1[q] = *(const float4*)(w1p + k0 + q * 4);
    }
    #pragma unroll
    for (int q = 0; q < 4; ++q) {
      #pragma unroll
      for (int r = 0; r < 8; ++r) {
        float4 a = *(const float4*)(hb + (size_t)r * H_DIM + k0 + q * 4); // uniform
        acc[r][0] = fmaf(a.x, b0[q].x, acc[r][0]);
        acc[r][0] = fmaf(a.y, b0[q].y, acc[r][0]);
        acc[r][0] = fmaf(a.z, b0[q].z, acc[r][0]);
        acc[r][0] = fmaf(a.w, b0[q].w, acc[r][0]);
        acc[r][1] = fmaf(a.x, b1[q].x, acc[r][1]);
        acc[r][1] = fmaf(a.y, b1[q].y, acc[r][1]);
        acc[r][1] = fmaf(a.z, b1[q].z, acc[r][1]);
        acc[r][1] = fmaf(a.w, b1[q].w, acc[r][1]);
      }
    }
  }

  const float fb0 = fcb[c0];
  const float fb1 = fcb[c0 + 1];
  #pragma unroll
  for (int r = 0; r < 8; ++r) {
    float z0 = acc[r][0] + fb0;
    float z1 = acc[r][1] + fb1;
    *(float2*)(out + (size_t)(r0 + r) * T * V_DIM + (size_t)t * V_DIM + c0)
        = make_float2(z0, z1);
    float v = z0; int ix = c0;
    if (z1 > v) { v = z1; ix = c0 + 1; }   // strict >: first index kept
    bv[r][tid] = v;
    bi[r][tid] = ix;
  }
  __syncthreads();

  #pragma unroll
  for (int rr = 0; rr < 2; ++rr) {
    int r = wv * 2 + rr;
    float best = bv[r][lane];
    int   bidx = bi[r][lane];
    #pragma unroll
    for (int s = 1; s < 4; ++s) {
      float ov = bv[r][lane + 64 * s];
      int   oi = bi[r][lane + 64 * s];
      if (ov > best || (ov == best && oi < bidx)) { best = ov; bidx = oi; }
    }
    #pragma unroll
    for (int off = 32; off; off >>= 1) {
      float ov = __shfl_xor(best, off);
      int   oi = __shfl_xor(bidx, off);
      if (ov > best || (ov == best && oi < bidx)) { best = ov; bidx = oi; }
    }
    if (lane == 0) tok[r0 + r] = bidx;
  }
}

extern "C" void kernel_launch(void* const* d_in, const int* in_sizes, int n_in,
                              void* d_out, int out_size, void* d_ws, size_t ws_size,
                              hipStream_t stream) {
  const int*   source  = (const int*)d_in[0];
  const float* enc_emb = (const float*)d_in[2];
  const float* enc_Wih = (const float*)d_in[3];
  const float* enc_Whh = (const float*)d_in[4];
  const float* enc_bih = (const float*)d_in[5];
  const float* enc_bhh = (const float*)d_in[6];
  const float* dec_emb = (const float*)d_in[7];
  const float* dec_Wih = (const float*)d_in[8];
  const float* dec_Whh = (const float*)d_in[9];
  const float* dec_bih = (const float*)d_in[10];
  const float* dec_bhh = (const float*)d_in[11];
  const float* fc_W    = (const float*)d_in[12];
  const float* fc_b    = (const float*)d_in[13];
  float* out = (float*)d_out;

  const int B = in_sizes[0] / S_LEN;              // 2048
  const int T = out_size / (B * V_DIM);           // 48

  const size_t BH = (size_t)B * H_DIM;
  const size_t WFSZ = (size_t)8 * W_TILES * TILE_SHORTS;   // shorts per set
  float* h0  = (float*)d_ws;
  float* h1  = h0 + BH;
  float* c   = h1 + BH;
  int*   tok = (int*)(c + BH);
  unsigned short* We = (unsigned short*)(tok + B);
  unsigned short* Wd = We + WFSZ;

  prep_weights<<<dim3(192 + 64), dim3(256), 0, stream>>>(
      enc_Wih, enc_Whh, dec_Wih, dec_Whh, We, Wd, h0, c, tok);

  dim3 blk(256);
  dim3 g_lstm(B / 32, H_DIM / 32);    // (64, 8) = 512 blocks, 2 blocks/CU
  dim3 g_declog(B / 8);               // 256 blocks

  const float* hin = h0;
  float* hout = h1;

  // ---- encoder ----
  for (int s = 0; s < S_LEN; ++s) {
    lstm_mfma_kernel<<<g_lstm, blk, 0, stream>>>(
        enc_emb, source, S_LEN, s, We, enc_bih, enc_bhh, hin, hout, c);
    const float* tmp = hout; hout = (float*)hin; hin = tmp;
  }

  // ---- decoder (greedy, autoregressive) ----
  for (int t = 0; t < T; ++t) {
    lstm_mfma_kernel<<<g_lstm, blk, 0, stream>>>(
        dec_emb, tok, 1, 0, Wd, dec_bih, dec_bhh, hin, hout, c);
    const float* tmp = hout; hout = (float*)hin; hin = tmp;
    declog_kernel<<<g_declog, blk, 0, stream>>>(hin, fc_W, fc_b, out, tok, t, T);
  }
}

// Round 18
// 1777.466 us; speedup vs baseline: 2.2740x; 1.1139x over previous
//
#include <hip/hip_runtime.h>
#include <cmath>

#define S_LEN 32
#define E_DIM 128
#define H_DIM 256
#define V_DIM 512
#define NTILE 18            // fp16 split: 0-5 a1w1, 6-11 a1w2s, 12-17 a2s*w1
#define W_TILES 12          // unique W tiles stored (tiles 12-17 reuse 0-5)
#define TILE_SHORTS 8192    // 16 frags x 64 lanes x 8 halfs = 16 KB
#define A_SHORTS 12288      // 24 k-chunks x 64 lanes x 8 halfs = 24 KB per level
#define ZPITCH 132          // z-buffer row pitch (words)

typedef _Float16 f16x8v __attribute__((ext_vector_type(8)));
typedef float f32x16 __attribute__((ext_vector_type(16)));

#define SCALE_S 4096.0f          // 2^12
#define INV_S   2.44140625e-4f   // 2^-12 (exact)

__device__ __forceinline__ float sigf(float x) { return 1.0f / (1.0f + expf(-x)); }

template<int L>
__device__ __forceinline__ unsigned short lvl_f16(float x) {
  _Float16 h1 = (_Float16)x;                       // RNE
  if (L == 1) return __builtin_bit_cast(unsigned short, h1);
  _Float16 h2 = (_Float16)((x - (float)h1) * SCALE_S);
  return __builtin_bit_cast(unsigned short, h2);
}

// ---------------------------------------------------------------------------
// prep: fp16 2-level fragment stream for 32x32x16 MFMA.
// Tile (BK=64) = 16 frags: fi = g*4 + kc (gate g, k-chunk kc of 16).
// Lane l supplies W row n = g*256 + nb*32 + (l&31), k = kk + (l>>5)*8 + e.
// Tiles 0..5 = w1, 6..11 = w2s. Blocks >= 192 zero-init h0/c/tok.
// ---------------------------------------------------------------------------
__global__ void prep_weights(const float* __restrict__ eWih, const float* __restrict__ eWhh,
                             const float* __restrict__ dWih, const float* __restrict__ dWhh,
                             unsigned short* __restrict__ We, unsigned short* __restrict__ Wd,
                             float* __restrict__ h0, float* __restrict__ c,
                             int* __restrict__ tok)
{
  const int b = blockIdx.x;
  if (b >= 192) {                         // ---- init tail: 64 blocks
    const int pb = b - 192;
    const int gt = pb * 256 + threadIdx.x;     // 0..16383
    float4 z = make_float4(0.f, 0.f, 0.f, 0.f);
    float4* p0 = (float4*)h0;
    float4* pc = (float4*)c;
    for (int i = gt; i < 131072; i += 16384) { p0[i] = z; pc[i] = z; }
    if (gt < 2048) tok[gt] = 0;
    return;
  }
  const int j    = b % W_TILES;           // 0..11
  const int rest = b / W_TILES;
  const int nb   = rest & 7;
  const int set  = rest >> 3;
  const float* Wih = set ? dWih : eWih;
  const float* Whh = set ? dWhh : eWhh;
  unsigned short* dst = (set ? Wd : We) + ((size_t)nb * W_TILES + j) * TILE_SHORTS;
  const int lvl = (j < 6) ? 1 : 2;
  const int jj  = (j < 6) ? j : j - 6;

  for (int cpos = threadIdx.x; cpos < 1024; cpos += 256) {
    int fi = cpos >> 6, l = cpos & 63;
    int g = fi >> 2, kc = fi & 3;
    int n  = g * H_DIM + nb * 32 + (l & 31);
    int kk = jj * 64 + kc * 16 + (l >> 5) * 8;
    unsigned short o8[8];
    #pragma unroll
    for (int e = 0; e < 8; ++e) {
      int k = kk + e;
      float v = (k < E_DIM) ? Wih[(size_t)n * E_DIM + k]
                            : Whh[(size_t)n * H_DIM + (k - E_DIM)];
      o8[e] = (lvl == 1) ? lvl_f16<1>(v) : lvl_f16<2>(v);
    }
    uint4 pk;
    pk.x = (unsigned)o8[0] | ((unsigned)o8[1] << 16);
    pk.y = (unsigned)o8[2] | ((unsigned)o8[3] << 16);
    pk.z = (unsigned)o8[4] | ((unsigned)o8[5] << 16);
    pk.w = (unsigned)o8[6] | ((unsigned)o8[7] << 16);
    *(uint4*)&dst[(size_t)cpos * 8] = pk;
  }
}

// stage BOTH fp16 levels of A=[emb[idx]|h_in] into 32x32x16 A-fragment layout:
// value (row, kA): chunk = kA>>4, lane = row + ((kA>>3)&1)*32, e = kA&7.
// Same split values as rounds 14-17.
__device__ __forceinline__ void stage_A12(unsigned short* Ax1, unsigned short* Ax2,
                                          const float* __restrict__ esrc,
                                          const float* __restrict__ hsrc,
                                          int arow, int q8) {
  #pragma unroll
  for (int j = 0; j < 12; ++j) {
    int k0, kA;
    const float* src;
    if (j < 4) { kA = q8 * 4 + 32 * j;            src = esrc + kA; }
    else       { k0 = q8 * 4 + 32 * (j - 4); kA = E_DIM + k0; src = hsrc + k0; }
    float4 v = *(const float4*)src;
    _Float16 a1x = (_Float16)v.x, a1y = (_Float16)v.y,
             a1z = (_Float16)v.z, a1w = (_Float16)v.w;
    _Float16 a2x = (_Float16)((v.x - (float)a1x) * SCALE_S);
    _Float16 a2y = (_Float16)((v.y - (float)a1y) * SCALE_S);
    _Float16 a2z = (_Float16)((v.z - (float)a1z) * SCALE_S);
    _Float16 a2w = (_Float16)((v.w - (float)a1w) * SCALE_S);
    int lane_w = arow + ((kA >> 3) & 1) * 32;
    int idx = (((kA >> 4)) * 64 + lane_w) * 8 + (kA & 7);
    uint2 p1, p2;
    p1.x = (unsigned)__builtin_bit_cast(unsigned short, a1x)
         | ((unsigned)__builtin_bit_cast(unsigned short, a1y) << 16);
    p1.y = (unsigned)__builtin_bit_cast(unsigned short, a1z)
         | ((unsigned)__builtin_bit_cast(unsigned short, a1w) << 16);
    p2.x = (unsigned)__builtin_bit_cast(unsigned short, a2x)
         | ((unsigned)__builtin_bit_cast(unsigned short, a2y) << 16);
    p2.y = (unsigned)__builtin_bit_cast(unsigned short, a2z)
         | ((unsigned)__builtin_bit_cast(unsigned short, a2w) << 16);
    *(uint2*)&Ax1[idx] = p1;
    *(uint2*)&Ax2[idx] = p2;
  }
}

// ---------------------------------------------------------------------------
// LSTM step, fp16 2-level 3-term split on 32x32x16 MFMA (gate-per-wave).
// Block: 32 rows x 32 hidden cols; wave w computes gate w (32x32 output).
// B operand bytes per wave HALVED vs 16x16x32 (4 frags/tile vs 8).
// Reg-streamed B (4 buffers, 3-tile lookahead), no per-tile barriers.
// C/D layout: col = lane&31, row = (reg&3) + 8*(reg>>2) + 4*(lane>>5).
// ---------------------------------------------------------------------------
__launch_bounds__(256, 2)
__global__ void lstm_mfma_kernel(const float* __restrict__ emb,
                                 const int* __restrict__ idx_src, int idx_stride, int idx_off,
                                 const unsigned short* __restrict__ Wf,
                                 const float* __restrict__ bih, const float* __restrict__ bhh,
                                 const float* __restrict__ h_in,
                                 float* __restrict__ h_out, float* __restrict__ c)
{
  __shared__ __align__(16) unsigned short smem[2 * A_SHORTS];  // 48 KB
  unsigned short* Ax1 = smem;                 // a1 fragments (z-buffer alias)
  unsigned short* Ax2 = smem + A_SHORTS;      // a2s fragments

  const int tid  = threadIdx.x;
  const int lane = tid & 63;
  const int w    = tid >> 6;            // wave = gate 0..3
  const int m0 = blockIdx.x * 32;
  const int nb = blockIdx.y;
  const int nc0 = nb * 32;

  const int arow = tid >> 3;            // 0..31
  const int q8   = tid & 7;
  const int token = idx_src[(size_t)(m0 + arow) * idx_stride + idx_off];
  const float* esrc = emb + (size_t)token * E_DIM;
  const float* hsrc = h_in + (size_t)(m0 + arow) * H_DIM;

  const int col32 = lane & 31;
  const int lhi   = lane >> 5;

  // per-wave B fragment base: frags (w*4 + kc), lane*8
  const unsigned short* wbase = Wf + (size_t)nb * (W_TILES * TILE_SHORTS)
                                   + (size_t)(w * 4) * 512 + (size_t)lane * 8;

  f32x16 accA, accB;
  #pragma unroll
  for (int r = 0; r < 16; ++r) { accA[r] = 0.f; accB[r] = 0.f; }

  uint4 pA[4], pB[4], pC[4], pD[4];

#define LOADT(J, P)                                                            \
  {                                                                            \
    const unsigned short* bsrc =                                               \
        wbase + (size_t)(((J) < W_TILES) ? (J) : (J) - W_TILES) * TILE_SHORTS; \
    _Pragma("unroll")                                                          \
    for (int kc = 0; kc < 4; ++kc) P[kc] = *(const uint4*)(bsrc + (size_t)kc * 512); \
  }

#define MFMAT(J, P, ACCX, AXB)                                                 \
  {                                                                            \
    const int jj = ((J) < 6) ? (J) : (((J) < 12) ? (J) - 6 : (J) - 12);        \
    _Pragma("unroll")                                                          \
    for (int kc = 0; kc < 4; ++kc) {                                           \
      f16x8v af = *(const f16x8v*)&AXB[(jj * 4 + kc) * 512 + lane * 8];        \
      f16x8v bfr = __builtin_bit_cast(f16x8v, P[kc]);                          \
      ACCX = __builtin_amdgcn_mfma_f32_32x32x16_f16(af, bfr, ACCX, 0, 0, 0);   \
    }                                                                          \
  }

  // issue first B tiles BEFORE A staging (their L2 latency hides under cvt)
  LOADT(0, pA); LOADT(1, pB); LOADT(2, pC);

  stage_A12(Ax1, Ax2, esrc, hsrc, arow, q8);
  asm volatile("s_waitcnt lgkmcnt(0)" ::: "memory");   // A writes visible
  __builtin_amdgcn_s_barrier();                        // B loads stay in flight

  LOADT(3, pD);  MFMAT(0, pA, accA, Ax1);
  LOADT(4, pA);  MFMAT(1, pB, accA, Ax1);
  LOADT(5, pB);  MFMAT(2, pC, accA, Ax1);
  LOADT(6, pC);  MFMAT(3, pD, accA, Ax1);
  LOADT(7, pD);  MFMAT(4, pA, accA, Ax1);
  LOADT(8, pA);  MFMAT(5, pB, accA, Ax1);
  LOADT(9, pB);  MFMAT(6, pC, accB, Ax1);
  LOADT(10, pC); MFMAT(7, pD, accB, Ax1);
  LOADT(11, pD); MFMAT(8, pA, accB, Ax1);
  LOADT(12, pA); MFMAT(9, pB, accB, Ax1);
  LOADT(13, pB); MFMAT(10, pC, accB, Ax1);
  LOADT(14, pC); MFMAT(11, pD, accB, Ax1);
  LOADT(15, pD); MFMAT(12, pA, accB, Ax2);
  LOADT(16, pA); MFMAT(13, pB, accB, Ax2);
  LOADT(17, pB); MFMAT(14, pC, accB, Ax2);

  // ---- reader-phase indices + c prefetch (covered by the last 3 MFMA tiles)
  const int er = tid >> 3;               // local row 0..31
  const int ec = tid & 7;                // float4-col 0..7
  const float* cp0 = c + (size_t)(m0 + er) * H_DIM + nc0 + ec * 4;
  float4 cold = *(const float4*)(cp0);

  MFMAT(15, pD, accB, Ax2);
  MFMAT(16, pA, accB, Ax2);
  MFMAT(17, pB, accB, Ax2);

#undef LOADT
#undef MFMAT

  // ---- epilogue stage 1: combine scales + bias -> z LDS buffer (reuse Ax1)
  const float bsv = bih[w * H_DIM + nc0 + col32] + bhh[w * H_DIM + nc0 + col32];

  float* zb = (float*)smem;
  asm volatile("s_waitcnt lgkmcnt(0)" ::: "memory");
  __builtin_amdgcn_s_barrier();          // all waves done reading Ax1/Ax2

  #pragma unroll
  for (int r = 0; r < 16; ++r) {
    int row_l = (r & 3) + 8 * (r >> 2) + 4 * lhi;
    zb[row_l * ZPITCH + col32 * 4 + w] = fmaf(accB[r], INV_S, accA[r]) + bsv;
  }

  asm volatile("s_waitcnt lgkmcnt(0)" ::: "memory");
  __builtin_amdgcn_s_barrier();          // z visible

  // ---- epilogue stage 2: cell update, coalesced float4 c/h I/O (r17 scheme)
  {
    float* hp  = h_out + (size_t)(m0 + er) * H_DIM + nc0 + ec * 4;
    float* cpw = (float*)cp0;
    float cov[4] = {cold.x, cold.y, cold.z, cold.w};
    float cnv[4], hnv[4];
    #pragma unroll
    for (int cc = 0; cc < 4; ++cc) {
      float4 zq = *(const float4*)&zb[er * ZPITCH + (ec * 4 + cc) * 4];
      float zi = zq.x, zf = zq.y, zg = zq.z, zo = zq.w;
      float cn = sigf(zf) * cov[cc] + sigf(zi) * tanhf(zg);
      cnv[cc] = cn;
      hnv[cc] = sigf(zo) * tanhf(cn);
    }
    *(float4*)cpw = make_float4(cnv[0], cnv[1], cnv[2], cnv[3]);
    *(float4*)hp  = make_float4(hnv[0], hnv[1], hnv[2], hnv[3]);
  }
}

// ---------------------------------------------------------------------------
// declog v4 — EXACT rounds 13-17 version (known-good, ~6 us).
// ---------------------------------------------------------------------------
__launch_bounds__(256)
__global__ void declog_kernel(const float* __restrict__ h,    // [B, H]
                              const float* __restrict__ fcW,  // [V, H]
                              const float* __restrict__ fcb,  // [V]
                              float* __restrict__ out,        // [B, T, V]
                              int* __restrict__ tok,          // [B]
                              int t, int T)
{
  __shared__ float bv[8][256];
  __shared__ int   bi[8][256];

  const int tid  = threadIdx.x;
  const int lane = tid & 63;
  const int wv   = tid >> 6;
  const int r0   = blockIdx.x * 8;
  const int c0   = tid * 2;             // this thread's 2 vocab cols

  const float* hb  = h + (size_t)r0 * H_DIM;
  const float* w0p = fcW + (size_t)c0 * H_DIM;
  const float* w1p = w0p + H_DIM;

  float acc[8][2] = {};                 // [row][col]

  #pragma unroll 1
  for (int k0 = 0; k0 < H_DIM; k0 += 16) {
    float4 b0[4], b1[4];
    #pragma unroll
    for (int q = 0; q < 4; ++q) {
      b0[q] = *(const float4*)(w0p + k0 + q * 4);
      b1[q] = *(const float4*)(w1p + k0 + q * 4);
    }
    #pragma unroll
    for (int q = 0; q < 4; ++q) {
      #pragma unroll
      for (int r = 0; r < 8; ++r) {
        float4 a = *(const float4*)(hb + (size_t)r * H_DIM + k0 + q * 4); // uniform
        acc[r][0] = fmaf(a.x, b0[q].x, acc[r][0]);
        acc[r][0] = fmaf(a.y, b0[q].y, acc[r][0]);
        acc[r][0] = fmaf(a.z, b0[q].z, acc[r][0]);
        acc[r][0] = fmaf(a.w, b0[q].w, acc[r][0]);
        acc[r][1] = fmaf(a.x, b1[q].x, acc[r][1]);
        acc[r][1] = fmaf(a.y, b1[q].y, acc[r][1]);
        acc[r][1] = fmaf(a.z, b1[q].z, acc[r][1]);
        acc[r][1] = fmaf(a.w, b1[q].w, acc[r][1]);
      }
    }
  }

  const float fb0 = fcb[c0];
  const float fb1 = fcb[c0 + 1];
  #pragma unroll
  for (int r = 0; r < 8; ++r) {
    float z0 = acc[r][0] + fb0;
    float z1 = acc[r][1] + fb1;
    *(float2*)(out + (size_t)(r0 + r) * T * V_DIM + (size_t)t * V_DIM + c0)
        = make_float2(z0, z1);
    float v = z0; int ix = c0;
    if (z1 > v) { v = z1; ix = c0 + 1; }   // strict >: first index kept
    bv[r][tid] = v;
    bi[r][tid] = ix;
  }
  __syncthreads();

  #pragma unroll
  for (int rr = 0; rr < 2; ++rr) {
    int r = wv * 2 + rr;
    float best = bv[r][lane];
    int   bidx = bi[r][lane];
    #pragma unroll
    for (int s = 1; s < 4; ++s) {
      float ov = bv[r][lane + 64 * s];
      int   oi = bi[r][lane + 64 * s];
      if (ov > best || (ov == best && oi < bidx)) { best = ov; bidx = oi; }
    }
    #pragma unroll
    for (int off = 32; off; off >>= 1) {
      float ov = __shfl_xor(best, off);
      int   oi = __shfl_xor(bidx, off);
      if (ov > best || (ov == best && oi < bidx)) { best = ov; bidx = oi; }
    }
    if (lane == 0) tok[r0 + r] = bidx;
  }
}

extern "C" void kernel_launch(void* const* d_in, const int* in_sizes, int n_in,
                              void* d_out, int out_size, void* d_ws, size_t ws_size,
                              hipStream_t stream) {
  const int*   source  = (const int*)d_in[0];
  const float* enc_emb = (const float*)d_in[2];
  const float* enc_Wih = (const float*)d_in[3];
  const float* enc_Whh = (const float*)d_in[4];
  const float* enc_bih = (const float*)d_in[5];
  const float* enc_bhh = (const float*)d_in[6];
  const float* dec_emb = (const float*)d_in[7];
  const float* dec_Wih = (const float*)d_in[8];
  const float* dec_Whh = (const float*)d_in[9];
  const float* dec_bih = (const float*)d_in[10];
  const float* dec_bhh = (const float*)d_in[11];
  const float* fc_W    = (const float*)d_in[12];
  const float* fc_b    = (const float*)d_in[13];
  float* out = (float*)d_out;

  const int B = in_sizes[0] / S_LEN;              // 2048
  const int T = out_size / (B * V_DIM);           // 48

  const size_t BH = (size_t)B * H_DIM;
  const size_t WFSZ = (size_t)8 * W_TILES * TILE_SHORTS;   // shorts per set
  float* h0  = (float*)d_ws;
  float* h1  = h0 + BH;
  float* c   = h1 + BH;
  int*   tok = (int*)(c + BH);
  unsigned short* We = (unsigned short*)(tok + B);
  unsigned short* Wd = We + WFSZ;

  prep_weights<<<dim3(192 + 64), dim3(256), 0, stream>>>(
      enc_Wih, enc_Whh, dec_Wih, dec_Whh, We, Wd, h0, c, tok);

  dim3 blk(256);
  dim3 g_lstm(B / 32, H_DIM / 32);    // (64, 8) = 512 blocks, 2 blocks/CU
  dim3 g_declog(B / 8);               // 256 blocks

  const float* hin = h0;
  float* hout = h1;

  // ---- encoder ----
  for (int s = 0; s < S_LEN; ++s) {
    lstm_mfma_kernel<<<g_lstm, blk, 0, stream>>>(
        enc_emb, source, S_LEN, s, We, enc_bih, enc_bhh, hin, hout, c);
    const float* tmp = hout; hout = (float*)hin; hin = tmp;
  }

  // ---- decoder (greedy, autoregressive) ----
  for (int t = 0; t < T; ++t) {
    lstm_mfma_kernel<<<g_lstm, blk, 0, stream>>>(
        dec_emb, tok, 1, 0, Wd, dec_bih, dec_bhh, hin, hout, c);
    const float* tmp = hout; hout = (float*)hin; hin = tmp;
    declog_kernel<<<g_declog, blk, 0, stream>>>(hin, fc_W, fc_b, out, tok, t, T);
  }
}

// Round 19
// 1679.002 us; speedup vs baseline: 2.4074x; 1.0586x over previous
//
#include <hip/hip_runtime.h>
#include <cmath>

#define S_LEN 32
#define E_DIM 128
#define H_DIM 256
#define V_DIM 512
#define NTILE 12            // h-only K=256: 0-3 a1w1, 4-7 a1w2s, 8-11 a2s*w1
#define W_TILES 8           // unique W tiles stored (tiles 8-11 reuse 0-3)
#define TILE_SHORTS 8192    // 16 frags x 64 lanes x 8 halfs = 16 KB
#define A_SHORTS 8192       // per level: 16 k-chunks x 64 lanes x 8 halfs = 16 KB
#define ZPITCH 132          // z-buffer row pitch (words)

typedef _Float16 f16x8v __attribute__((ext_vector_type(8)));
typedef float f32x16 __attribute__((ext_vector_type(16)));

#define SCALE_S 4096.0f          // 2^12
#define INV_S   2.44140625e-4f   // 2^-12 (exact)

__device__ __forceinline__ float sigf(float x) { return 1.0f / (1.0f + expf(-x)); }

template<int L>
__device__ __forceinline__ unsigned short lvl_f16(float x) {
  _Float16 h1 = (_Float16)x;                       // RNE
  if (L == 1) return __builtin_bit_cast(unsigned short, h1);
  _Float16 h2 = (_Float16)((x - (float)h1) * SCALE_S);
  return __builtin_bit_cast(unsigned short, h2);
}

// ---------------------------------------------------------------------------
// prep, 3 roles by blockIdx:
//  [0,128):    Whh fragment stream (h-only K=256), fp16 2-level, 32x32x16
//              layout (r18-proven): fi=g*4+kc, lane row n=g*256+nb*32+(l&31),
//              k = jj*64 + kc*16 + (l>>5)*8 + e. Tiles 0-3 w1, 4-7 w2s.
//  [128,1152): precomp P[set][v][n] = emb[v] @ Wih[n]^T, exact f32, k ascending.
//  [1152,1216): zero-init h0 / c / tok.
// ---------------------------------------------------------------------------
__global__ void prep_weights(const float* __restrict__ eemb, const float* __restrict__ demb,
                             const float* __restrict__ eWih, const float* __restrict__ eWhh,
                             const float* __restrict__ dWih, const float* __restrict__ dWhh,
                             unsigned short* __restrict__ We, unsigned short* __restrict__ Wd,
                             float* __restrict__ PE, float* __restrict__ PD,
                             float* __restrict__ h0, float* __restrict__ c,
                             int* __restrict__ tok)
{
  const int b = blockIdx.x;
  if (b >= 1152) {                        // ---- init tail: 64 blocks
    const int pb = b - 1152;
    const int gt = pb * 256 + threadIdx.x;     // 0..16383
    float4 z = make_float4(0.f, 0.f, 0.f, 0.f);
    float4* p0 = (float4*)h0;
    float4* pc = (float4*)c;
    for (int i = gt; i < 131072; i += 16384) { p0[i] = z; pc[i] = z; }
    if (gt < 2048) tok[gt] = 0;
    return;
  }
  if (b >= 128) {                         // ---- precomp: 1024 blocks
    const int pb  = b - 128;
    const int set = pb >> 9;              // 0 enc, 1 dec
    const int v   = pb & 511;
    const float* Wih  = set ? dWih : eWih;
    const float* embr = (set ? demb : eemb) + (size_t)v * E_DIM;
    float* dst = (set ? PD : PE) + (size_t)v * 1024;
    const int n0 = threadIdx.x * 4;
    float acc[4] = {0.f, 0.f, 0.f, 0.f};
    #pragma unroll 4
    for (int k0 = 0; k0 < E_DIM; k0 += 4) {
      float4 e = *(const float4*)(embr + k0);
      #pragma unroll
      for (int i = 0; i < 4; ++i) {
        float4 wv = *(const float4*)(Wih + (size_t)(n0 + i) * E_DIM + k0);
        acc[i] = fmaf(e.x, wv.x, acc[i]);
        acc[i] = fmaf(e.y, wv.y, acc[i]);
        acc[i] = fmaf(e.z, wv.z, acc[i]);
        acc[i] = fmaf(e.w, wv.w, acc[i]);
      }
    }
    *(float4*)(dst + n0) = make_float4(acc[0], acc[1], acc[2], acc[3]);
    return;
  }
  // ---- Whh fragment stream: 128 blocks
  const int j    = b % W_TILES;           // 0..7
  const int rest = b / W_TILES;
  const int nb   = rest & 7;
  const int set  = rest >> 3;
  const float* Whh = set ? dWhh : eWhh;
  unsigned short* dst = (set ? Wd : We) + ((size_t)nb * W_TILES + j) * TILE_SHORTS;
  const int lvl = (j < 4) ? 1 : 2;
  const int jj  = j & 3;

  for (int cpos = threadIdx.x; cpos < 1024; cpos += 256) {
    int fi = cpos >> 6, l = cpos & 63;
    int g = fi >> 2, kc = fi & 3;
    int n  = g * H_DIM + nb * 32 + (l & 31);
    int kk = jj * 64 + kc * 16 + (l >> 5) * 8;
    unsigned short o8[8];
    #pragma unroll
    for (int e = 0; e < 8; ++e) {
      float v = Whh[(size_t)n * H_DIM + kk + e];
      o8[e] = (lvl == 1) ? lvl_f16<1>(v) : lvl_f16<2>(v);
    }
    uint4 pk;
    pk.x = (unsigned)o8[0] | ((unsigned)o8[1] << 16);
    pk.y = (unsigned)o8[2] | ((unsigned)o8[3] << 16);
    pk.z = (unsigned)o8[4] | ((unsigned)o8[5] << 16);
    pk.w = (unsigned)o8[6] | ((unsigned)o8[7] << 16);
    *(uint4*)&dst[(size_t)cpos * 8] = pk;
  }
}

// stage BOTH fp16 levels of A = h_in (K=256) into 32x32x16 A-fragment layout:
// value (row, kA): chunk = kA>>4, lane = row + ((kA>>3)&1)*32, e = kA&7.
__device__ __forceinline__ void stage_A12(unsigned short* Ax1, unsigned short* Ax2,
                                          const float* __restrict__ hsrc,
                                          int arow, int q8) {
  #pragma unroll
  for (int j = 0; j < 8; ++j) {
    int kA = q8 * 4 + 32 * j;                 // covers 0..255 (multiples of 4)
    float4 v = *(const float4*)(hsrc + kA);
    _Float16 a1x = (_Float16)v.x, a1y = (_Float16)v.y,
             a1z = (_Float16)v.z, a1w = (_Float16)v.w;
    _Float16 a2x = (_Float16)((v.x - (float)a1x) * SCALE_S);
    _Float16 a2y = (_Float16)((v.y - (float)a1y) * SCALE_S);
    _Float16 a2z = (_Float16)((v.z - (float)a1z) * SCALE_S);
    _Float16 a2w = (_Float16)((v.w - (float)a1w) * SCALE_S);
    int lane_w = arow + ((kA >> 3) & 1) * 32;
    int idx = ((kA >> 4) * 64 + lane_w) * 8 + (kA & 7);
    uint2 p1, p2;
    p1.x = (unsigned)__builtin_bit_cast(unsigned short, a1x)
         | ((unsigned)__builtin_bit_cast(unsigned short, a1y) << 16);
    p1.y = (unsigned)__builtin_bit_cast(unsigned short, a1z)
         | ((unsigned)__builtin_bit_cast(unsigned short, a1w) << 16);
    p2.x = (unsigned)__builtin_bit_cast(unsigned short, a2x)
         | ((unsigned)__builtin_bit_cast(unsigned short, a2y) << 16);
    p2.y = (unsigned)__builtin_bit_cast(unsigned short, a2z)
         | ((unsigned)__builtin_bit_cast(unsigned short, a2w) << 16);
    *(uint2*)&Ax1[idx] = p1;
    *(uint2*)&Ax2[idx] = p2;
  }
}

// ---------------------------------------------------------------------------
// LSTM step: h-part GEMM (K=256, fp16 2-level 3-term, 32x32x16 gate-per-wave)
// + precomputed x-part added in the epilogue (exact f32 from P[token]).
// Block: 32 rows x 32 hidden cols; wave w = gate w. 12 tiles, reg-streamed B
// (4 buffers, 3-tile lookahead), no per-tile barriers. LDS 32 KB.
// ---------------------------------------------------------------------------
__launch_bounds__(256, 2)
__global__ void lstm_mfma_kernel(const float* __restrict__ pcomp,   // [512][1024]
                                 const int* __restrict__ idx_src, int idx_stride, int idx_off,
                                 const unsigned short* __restrict__ Wf,
                                 const float* __restrict__ bih, const float* __restrict__ bhh,
                                 const float* __restrict__ h_in,
                                 float* __restrict__ h_out, float* __restrict__ c)
{
  __shared__ __align__(16) unsigned short smem[2 * A_SHORTS];  // 32 KB
  unsigned short* Ax1 = smem;                 // a1 fragments (z-buffer alias)
  unsigned short* Ax2 = smem + A_SHORTS;      // a2s fragments

  const int tid  = threadIdx.x;
  const int lane = tid & 63;
  const int w    = tid >> 6;            // wave = gate 0..3
  const int m0 = blockIdx.x * 32;
  const int nb = blockIdx.y;
  const int nc0 = nb * 32;

  const int arow = tid >> 3;            // 0..31 (also epilogue row er)
  const int q8   = tid & 7;             // (also epilogue col group ec)
  const int token = idx_src[(size_t)(m0 + arow) * idx_stride + idx_off];
  const float* hsrc = h_in + (size_t)(m0 + arow) * H_DIM;

  const int col32 = lane & 31;
  const int lhi   = lane >> 5;

  // per-wave B fragment base: frags (w*4 + kc), lane*8
  const unsigned short* wbase = Wf + (size_t)nb * (W_TILES * TILE_SHORTS)
                                   + (size_t)(w * 4) * 512 + (size_t)lane * 8;

  f32x16 accA, accB;
  #pragma unroll
  for (int r = 0; r < 16; ++r) { accA[r] = 0.f; accB[r] = 0.f; }

  uint4 pA[4], pB[4], pC[4], pD[4];

#define LOADT(J, P)                                                            \
  {                                                                            \
    const unsigned short* bsrc = wbase + (size_t)((J) & 7) * TILE_SHORTS;      \
    _Pragma("unroll")                                                          \
    for (int kc = 0; kc < 4; ++kc) P[kc] = *(const uint4*)(bsrc + (size_t)kc * 512); \
  }

#define MFMAT(J, P, ACCX, AXB)                                                 \
  {                                                                            \
    _Pragma("unroll")                                                          \
    for (int kc = 0; kc < 4; ++kc) {                                           \
      f16x8v af = *(const f16x8v*)&AXB[(((J) & 3) * 4 + kc) * 512 + lane * 8]; \
      f16x8v bfr = __builtin_bit_cast(f16x8v, P[kc]);                          \
      ACCX = __builtin_amdgcn_mfma_f32_32x32x16_f16(af, bfr, ACCX, 0, 0, 0);   \
    }                                                                          \
  }

  // issue first B tiles BEFORE A staging (their L2 latency hides under cvt)
  LOADT(0, pA); LOADT(1, pB); LOADT(2, pC);

  stage_A12(Ax1, Ax2, hsrc, arow, q8);
  asm volatile("s_waitcnt lgkmcnt(0)" ::: "memory");   // A writes visible
  __builtin_amdgcn_s_barrier();                        // B loads stay in flight

  LOADT(3, pD);  MFMAT(0, pA, accA, Ax1);
  LOADT(4, pA);  MFMAT(1, pB, accA, Ax1);
  LOADT(5, pB);  MFMAT(2, pC, accA, Ax1);
  LOADT(6, pC);  MFMAT(3, pD, accA, Ax1);
  LOADT(7, pD);  MFMAT(4, pA, accB, Ax1);
  LOADT(8, pA);  MFMAT(5, pB, accB, Ax1);
  LOADT(9, pB);  MFMAT(6, pC, accB, Ax1);
  LOADT(10, pC); MFMAT(7, pD, accB, Ax1);
  LOADT(11, pD); MFMAT(8, pA, accB, Ax2);

  // ---- prefetch c and precomp-x rows (covered by the last 3 MFMA tiles)
  const int er = arow;                   // local row 0..31
  const int ec = q8;                     // float4-col 0..7
  const float* cp0 = c + (size_t)(m0 + er) * H_DIM + nc0 + ec * 4;
  float4 cold = *(const float4*)(cp0);
  const float* pxr = pcomp + (size_t)token * 1024 + nc0 + ec * 4;
  float pxa[4][4];
  #pragma unroll
  for (int g = 0; g < 4; ++g) {
    float4 t = *(const float4*)(pxr + g * H_DIM);
    pxa[g][0] = t.x; pxa[g][1] = t.y; pxa[g][2] = t.z; pxa[g][3] = t.w;
  }

  MFMAT(9, pB, accB, Ax2);
  MFMAT(10, pC, accB, Ax2);
  MFMAT(11, pD, accB, Ax2);

#undef LOADT
#undef MFMAT

  // ---- epilogue stage 1: combine scales + bias -> z LDS buffer (alias A)
  const float bsv = bih[w * H_DIM + nc0 + col32] + bhh[w * H_DIM + nc0 + col32];

  float* zb = (float*)smem;
  asm volatile("s_waitcnt lgkmcnt(0)" ::: "memory");
  __builtin_amdgcn_s_barrier();          // all waves done reading Ax1/Ax2

  #pragma unroll
  for (int r = 0; r < 16; ++r) {
    int row_l = (r & 3) + 8 * (r >> 2) + 4 * lhi;
    zb[row_l * ZPITCH + col32 * 4 + w] = fmaf(accB[r], INV_S, accA[r]) + bsv;
  }

  asm volatile("s_waitcnt lgkmcnt(0)" ::: "memory");
  __builtin_amdgcn_s_barrier();          // z visible

  // ---- epilogue stage 2: z += precomp-x, cell update, coalesced f4 c/h I/O
  {
    float* hp  = h_out + (size_t)(m0 + er) * H_DIM + nc0 + ec * 4;
    float* cpw = (float*)cp0;
    float cov[4] = {cold.x, cold.y, cold.z, cold.w};
    float cnv[4], hnv[4];
    #pragma unroll
    for (int cc = 0; cc < 4; ++cc) {
      float4 zq = *(const float4*)&zb[er * ZPITCH + (ec * 4 + cc) * 4];
      float zi = zq.x + pxa[0][cc];
      float zf = zq.y + pxa[1][cc];
      float zg = zq.z + pxa[2][cc];
      float zo = zq.w + pxa[3][cc];
      float cn = sigf(zf) * cov[cc] + sigf(zi) * tanhf(zg);
      cnv[cc] = cn;
      hnv[cc] = sigf(zo) * tanhf(cn);
    }
    *(float4*)cpw = make_float4(cnv[0], cnv[1], cnv[2], cnv[3]);
    *(float4*)hp  = make_float4(hnv[0], hnv[1], hnv[2], hnv[3]);
  }
}

// ---------------------------------------------------------------------------
// declog v4 — EXACT rounds 13-18 version (known-good, ~6 us).
// ---------------------------------------------------------------------------
__launch_bounds__(256)
__global__ void declog_kernel(const float* __restrict__ h,    // [B, H]
                              const float* __restrict__ fcW,  // [V, H]
                              const float* __restrict__ fcb,  // [V]
                              float* __restrict__ out,        // [B, T, V]
                              int* __restrict__ tok,          // [B]
                              int t, int T)
{
  __shared__ float bv[8][256];
  __shared__ int   bi[8][256];

  const int tid  = threadIdx.x;
  const int lane = tid & 63;
  const int wv   = tid >> 6;
  const int r0   = blockIdx.x * 8;
  const int c0   = tid * 2;             // this thread's 2 vocab cols

  const float* hb  = h + (size_t)r0 * H_DIM;
  const float* w0p = fcW + (size_t)c0 * H_DIM;
  const float* w1p = w0p + H_DIM;

  float acc[8][2] = {};                 // [row][col]

  #pragma unroll 1
  for (int k0 = 0; k0 < H_DIM; k0 += 16) {
    float4 b0[4], b1[4];
    #pragma unroll
    for (int q = 0; q < 4; ++q) {
      b0[q] = *(const float4*)(w0p + k0 + q * 4);
      b1[q] = *(const float4*)(w1p + k0 + q * 4);
    }
    #pragma unroll
    for (int q = 0; q < 4; ++q) {
      #pragma unroll
      for (int r = 0; r < 8; ++r) {
        float4 a = *(const float4*)(hb + (size_t)r * H_DIM + k0 + q * 4); // uniform
        acc[r][0] = fmaf(a.x, b0[q].x, acc[r][0]);
        acc[r][0] = fmaf(a.y, b0[q].y, acc[r][0]);
        acc[r][0] = fmaf(a.z, b0[q].z, acc[r][0]);
        acc[r][0] = fmaf(a.w, b0[q].w, acc[r][0]);
        acc[r][1] = fmaf(a.x, b1[q].x, acc[r][1]);
        acc[r][1] = fmaf(a.y, b1[q].y, acc[r][1]);
        acc[r][1] = fmaf(a.z, b1[q].z, acc[r][1]);
        acc[r][1] = fmaf(a.w, b1[q].w, acc[r][1]);
      }
    }
  }

  const float fb0 = fcb[c0];
  const float fb1 = fcb[c0 + 1];
  #pragma unroll
  for (int r = 0; r < 8; ++r) {
    float z0 = acc[r][0] + fb0;
    float z1 = acc[r][1] + fb1;
    *(float2*)(out + (size_t)(r0 + r) * T * V_DIM + (size_t)t * V_DIM + c0)
        = make_float2(z0, z1);
    float v = z0; int ix = c0;
    if (z1 > v) { v = z1; ix = c0 + 1; }   // strict >: first index kept
    bv[r][tid] = v;
    bi[r][tid] = ix;
  }
  __syncthreads();

  #pragma unroll
  for (int rr = 0; rr < 2; ++rr) {
    int r = wv * 2 + rr;
    float best = bv[r][lane];
    int   bidx = bi[r][lane];
    #pragma unroll
    for (int s = 1; s < 4; ++s) {
      float ov = bv[r][lane + 64 * s];
      int   oi = bi[r][lane + 64 * s];
      if (ov > best || (ov == best && oi < bidx)) { best = ov; bidx = oi; }
    }
    #pragma unroll
    for (int off = 32; off; off >>= 1) {
      float ov = __shfl_xor(best, off);
      int   oi = __shfl_xor(bidx, off);
      if (ov > best || (ov == best && oi < bidx)) { best = ov; bidx = oi; }
    }
    if (lane == 0) tok[r0 + r] = bidx;
  }
}

extern "C" void kernel_launch(void* const* d_in, const int* in_sizes, int n_in,
                              void* d_out, int out_size, void* d_ws, size_t ws_size,
                              hipStream_t stream) {
  const int*   source  = (const int*)d_in[0];
  const float* enc_emb = (const float*)d_in[2];
  const float* enc_Wih = (const float*)d_in[3];
  const float* enc_Whh = (const float*)d_in[4];
  const float* enc_bih = (const float*)d_in[5];
  const float* enc_bhh = (const float*)d_in[6];
  const float* dec_emb = (const float*)d_in[7];
  const float* dec_Wih = (const float*)d_in[8];
  const float* dec_Whh = (const float*)d_in[9];
  const float* dec_bih = (const float*)d_in[10];
  const float* dec_bhh = (const float*)d_in[11];
  const float* fc_W    = (const float*)d_in[12];
  const float* fc_b    = (const float*)d_in[13];
  float* out = (float*)d_out;

  const int B = in_sizes[0] / S_LEN;              // 2048
  const int T = out_size / (B * V_DIM);           // 48

  const size_t BH = (size_t)B * H_DIM;
  const size_t WFSZ = (size_t)8 * W_TILES * TILE_SHORTS;   // shorts per set (1 MB)
  float* h0  = (float*)d_ws;
  float* h1  = h0 + BH;
  float* c   = h1 + BH;
  int*   tok = (int*)(c + BH);
  unsigned short* We = (unsigned short*)(tok + B);
  unsigned short* Wd = We + WFSZ;
  float* PE = (float*)(Wd + WFSZ);                // [512][1024] f32
  float* PD = PE + (size_t)V_DIM * 1024;

  prep_weights<<<dim3(128 + 1024 + 64), dim3(256), 0, stream>>>(
      enc_emb, dec_emb, enc_Wih, enc_Whh, dec_Wih, dec_Whh,
      We, Wd, PE, PD, h0, c, tok);

  dim3 blk(256);
  dim3 g_lstm(B / 32, H_DIM / 32);    // (64, 8) = 512 blocks, 2 blocks/CU
  dim3 g_declog(B / 8);               // 256 blocks

  const float* hin = h0;
  float* hout = h1;

  // ---- encoder ----
  for (int s = 0; s < S_LEN; ++s) {
    lstm_mfma_kernel<<<g_lstm, blk, 0, stream>>>(
        PE, source, S_LEN, s, We, enc_bih, enc_bhh, hin, hout, c);
    const float* tmp = hout; hout = (float*)hin; hin = tmp;
  }

  // ---- decoder (greedy, autoregressive) ----
  for (int t = 0; t < T; ++t) {
    lstm_mfma_kernel<<<g_lstm, blk, 0, stream>>>(
        PD, tok, 1, 0, Wd, dec_bih, dec_bhh, hin, hout, c);
    const float* tmp = hout; hout = (float*)hin; hin = tmp;
    declog_kernel<<<g_declog, blk, 0, stream>>>(hin, fc_W, fc_b, out, tok, t, T);
  }
}